// Round 17
// baseline (301.976 us; speedup 1.0000x reference)
//
#include <hip/hip_runtime.h>
#include <stdint.h>

#define DEV __device__ __forceinline__

// ---------- problem constants ----------
#define BP 96
#define NTOK 196
#define DIM 512
#define HID 256
#define NS 500
#define TOPK 49
#define ROWS (BP * NTOK)          // 18816
#define GBLK (ROWS / 32)          // 588 blocks for MFMA GEMMs
#define SPB 10                    // sample-chunks per frame-batch
#define CNTSZ (TOPK * NTOK)       // 9604

typedef _Float16 f16x8 __attribute__((ext_vector_type(8)));
typedef float f32x4 __attribute__((ext_vector_type(4)));

// ---------- math helpers ----------
DEV float gelu32(float v) {
  return 0.5f * v * (1.0f + erff(v * 0.70710678f));
}

// Threefry-2x32, 20 rounds, key = (0, 1)  (jax.random.key(1))
DEV void threefry2x32(uint32_t x0, uint32_t x1, uint32_t& o0, uint32_t& o1) {
  const uint32_t k0 = 0u, k1 = 1u;
  const uint32_t k2 = 0x1BD11BDAu ^ k0 ^ k1;
  x0 += k0; x1 += k1;
#define TF_R(r) { x0 += x1; x1 = (x1 << (r)) | (x1 >> (32 - (r))); x1 ^= x0; }
  TF_R(13) TF_R(15) TF_R(26) TF_R(6)
  x0 += k1; x1 += k2 + 1u;
  TF_R(17) TF_R(29) TF_R(16) TF_R(24)
  x0 += k2; x1 += k0 + 2u;
  TF_R(13) TF_R(15) TF_R(26) TF_R(6)
  x0 += k0; x1 += k1 + 3u;
  TF_R(17) TF_R(29) TF_R(16) TF_R(24)
  x0 += k1; x1 += k2 + 4u;
  TF_R(13) TF_R(15) TF_R(26) TF_R(6)
  x0 += k2; x1 += k0 + 5u;
#undef TF_R
  o0 = x0; o1 = x1;
}

// XLA ErfInv32 (Giles polynomial). w via native v_log_f32 (flip-safe, r13-proven)
DEV float erfinv_xla(float x) {
  float w = -__logf(fmaf(-x, x, 1.0f));
  float ws = w - 2.5f;
  float ps = 2.81022636e-08f;
  ps = fmaf(ps, ws, 3.43273939e-07f);
  ps = fmaf(ps, ws, -3.5233877e-06f);
  ps = fmaf(ps, ws, -4.39150654e-06f);
  ps = fmaf(ps, ws, 0.00021858087f);
  ps = fmaf(ps, ws, -0.00125372503f);
  ps = fmaf(ps, ws, -0.00417768164f);
  ps = fmaf(ps, ws, 0.246640727f);
  ps = fmaf(ps, ws, 1.50140941f);
  float r = ps;
  if (__ballot(w >= 5.0f) != 0ull) {
    float wl = sqrtf(w) - 3.0f;
    float pl = -0.000200214257f;
    pl = fmaf(pl, wl, 0.000100950558f);
    pl = fmaf(pl, wl, 0.00134934322f);
    pl = fmaf(pl, wl, -0.00367342844f);
    pl = fmaf(pl, wl, 0.00573950773f);
    pl = fmaf(pl, wl, -0.0076224613f);
    pl = fmaf(pl, wl, 0.00943887047f);
    pl = fmaf(pl, wl, 1.00167406f);
    pl = fmaf(pl, wl, 2.83297682f);
    r = (w < 5.0f) ? ps : pl;
  }
  return r * x;
}

// jax-f32-faithful N(0,1) noise, PARTITIONABLE threefry: counter=(0,g), draw=o0^o1
DEV float noise_at(unsigned g) {
  unsigned o0, o1;
  threefry2x32(0u, g, o0, o1);
  unsigned bits = o0 ^ o1;
  float f = __uint_as_float((bits >> 9) | 0x3f800000u) - 1.0f;
  float u = f * 2.0f - 0.99999994f;
  u = fmaxf(-0.99999994f, u);
  return 1.41421356f * erfinv_xla(u);
}

// fragment-major weight packing: P[((t*4+kg)*256 + col)*8 + e] = W[k=t*32+kg*8+e][col]
DEV size_t pack_idx(int k, int col) {
  int t = k >> 5, kg = (k >> 3) & 3, e = k & 7;
  return (((size_t)(t * 4 + kg) * 256) + col) * 8 + e;
}

// ---------- K0: merged pre-pass: glob (192) | wprep (512) | stats (4704) ----------
#define PRE_GLOB 192
#define PRE_PREP 512
#define PRE_STATS (ROWS / 4)
__global__ __launch_bounds__(256) void k_pre(
    const float* __restrict__ gf, const float* __restrict__ gs,
    const float* __restrict__ lng, const float* __restrict__ lnb,
    const float* __restrict__ Wgd, const float* __restrict__ Wout1,
    float* __restrict__ cout,
    const float* __restrict__ Win,
    const float* __restrict__ g_in, const float* __restrict__ b_in,
    _Float16* __restrict__ Pgh, _Float16* __restrict__ Pgl,
    _Float16* __restrict__ P1h, _Float16* __restrict__ P1l,
    float* __restrict__ gwv, float* __restrict__ bwv,
    const float* __restrict__ x, float* __restrict__ stats) {
  const int bid = blockIdx.x;
  if (bid < PRE_GLOB) {
    int bq = bid >> 1, which = bid & 1;
    const float* row = which ? (gs + (size_t)(bq / 12) * DIM) : (gf + (size_t)bq * DIM);
    __shared__ float lx[DIM];
    __shared__ float sg[HID];
    __shared__ double sred[8];
    int tid = threadIdx.x, lane = tid & 63, wv = tid >> 6;
    float v0 = row[tid], v1 = row[tid + 256];
    double s = (double)v0 + v1, q = (double)v0 * v0 + (double)v1 * v1;
    #pragma unroll
    for (int m = 1; m < 64; m <<= 1) { s += __shfl_xor(s, m); q += __shfl_xor(q, m); }
    if (lane == 0) { sred[wv * 2] = s; sred[wv * 2 + 1] = q; }
    __syncthreads();
    double ts = sred[0] + sred[2] + sred[4] + sred[6];
    double tq = sred[1] + sred[3] + sred[5] + sred[7];
    double mean = ts / 512.0;
    double var = tq / 512.0 - mean * mean;
    float mn = (float)mean;
    float rs = (float)(1.0 / sqrt(var + 1e-5));
    lx[tid]       = (v0 - mn) * rs * lng[tid] + lnb[tid];
    lx[tid + 256] = (v1 - mn) * rs * lng[tid + 256] + lnb[tid + 256];
    __syncthreads();
    float acc = 0.0f;
    for (int d = 0; d < DIM; ++d) acc = fmaf(lx[d], Wgd[(size_t)d * HID + tid], acc);
    sg[tid] = gelu32(acc);
    __syncthreads();
    float c = 0.0f;
    for (int j = 0; j < HID; ++j) c = fmaf(sg[j], Wout1[(size_t)(HID + j) * HID + tid], c);
    cout[((size_t)which * BP + bq) * HID + tid] = c;
  } else if (bid < PRE_GLOB + PRE_PREP) {
    int b2 = bid - PRE_GLOB;
    int n = b2 & 255, half = b2 >> 8;
    if (half == 0) {
      __shared__ float wred[8];
      int tid = threadIdx.x, lane = tid & 63, wv = tid >> 6;
      float sgv = 0.0f, sbv = 0.0f;
      #pragma unroll
      for (int kk = 0; kk < 2; ++kk) {
        int k = tid + kk * 256;
        float w = Win[(size_t)k * HID + n];
        float wg = w * g_in[k];
        _Float16 h = (_Float16)wg;
        size_t pi = pack_idx(k, n);
        Pgh[pi] = h;
        Pgl[pi] = (_Float16)(wg - (float)h);
        sgv += wg;
        sbv = fmaf(b_in[k], w, sbv);
      }
      #pragma unroll
      for (int m = 1; m < 64; m <<= 1) { sgv += __shfl_xor(sgv, m); sbv += __shfl_xor(sbv, m); }
      if (lane == 0) { wred[wv * 2] = sgv; wred[wv * 2 + 1] = sbv; }
      __syncthreads();
      if (tid == 0) {
        gwv[n] = wred[0] + wred[2] + wred[4] + wred[6];
        bwv[n] = wred[1] + wred[3] + wred[5] + wred[7];
      }
    } else {
      int k = threadIdx.x;
      float v = Wout1[(size_t)k * HID + n];
      _Float16 h = (_Float16)v;
      size_t pi = pack_idx(k, n);
      P1h[pi] = h;
      P1l[pi] = (_Float16)(v - (float)h);
    }
  } else {
    int r = (bid - PRE_GLOB - PRE_PREP) * 4 + (threadIdx.x >> 6);
    int lane = threadIdx.x & 63;
    const float4* xr = (const float4*)(x + (size_t)r * DIM);
    float4 a = xr[lane], c = xr[lane + 64];
    double s = (double)a.x + a.y + a.z + a.w + (double)c.x + c.y + c.z + c.w;
    double q = (double)a.x * a.x + (double)a.y * a.y + (double)a.z * a.z + (double)a.w * a.w +
               (double)c.x * c.x + (double)c.y * c.y + (double)c.z * c.z + (double)c.w * c.w;
    #pragma unroll
    for (int m = 1; m < 64; m <<= 1) { s += __shfl_xor(s, m); q += __shfl_xor(q, m); }
    if (lane == 0) {
      double mean = s / 512.0;
      double var = q / 512.0 - mean * mean;
      stats[r * 2]     = (float)mean;
      stats[r * 2 + 1] = (float)(1.0 / sqrt(var + 1e-5));
    }
  }
}

// ---------- shared GEMM machinery: all-register, no LDS in loop ----------
#define LOADA(src0, src1, t, pb)                                               \
  {                                                                            \
    axv[pb][0] = *(const float4*)((src0) + (t) * 32);                          \
    axv[pb][1] = *(const float4*)((src0) + (t) * 32 + 4);                      \
    axv[pb][2] = *(const float4*)((src1) + (t) * 32);                          \
    axv[pb][3] = *(const float4*)((src1) + (t) * 32 + 4);                      \
  }

#define LOADB(bh, bl, t, pb)                                                   \
  {                                                                            \
    _Pragma("unroll")                                                          \
    for (int ni = 0; ni < 4; ++ni) {                                           \
      bxh[pb][ni] = *(const f16x8*)((bh) + (size_t)(t) * 8192 + ni * 128);     \
      bxl[pb][ni] = *(const f16x8*)((bl) + (size_t)(t) * 8192 + ni * 128);     \
    }                                                                          \
  }

#define SPLITA(pb, fah, fal)                                                   \
  {                                                                            \
    _Pragma("unroll")                                                          \
    for (int mi = 0; mi < 2; ++mi) {                                           \
      float va[8];                                                             \
      *(float4*)&va[0] = axv[pb][mi * 2];                                      \
      *(float4*)&va[4] = axv[pb][mi * 2 + 1];                                  \
      _Pragma("unroll")                                                        \
      for (int e = 0; e < 8; ++e) {                                            \
        _Float16 h = (_Float16)va[e];                                          \
        fah[mi][e] = h;                                                        \
        fal[mi][e] = (_Float16)(va[e] - (float)h);                             \
      }                                                                        \
    }                                                                          \
  }

#define MFMA_CHUNK(pb, fah, fal)                                               \
  {                                                                            \
    _Pragma("unroll")                                                          \
    for (int mi = 0; mi < 2; ++mi)                                             \
      _Pragma("unroll")                                                        \
      for (int ni = 0; ni < 4; ++ni) {                                         \
        acc[mi][ni] = __builtin_amdgcn_mfma_f32_16x16x32_f16(fah[mi], bxh[pb][ni], acc[mi][ni], 0, 0, 0); \
        acc[mi][ni] = __builtin_amdgcn_mfma_f32_16x16x32_f16(fah[mi], bxl[pb][ni], acc[mi][ni], 0, 0, 0); \
        acc[mi][ni] = __builtin_amdgcn_mfma_f32_16x16x32_f16(fal[mi], bxh[pb][ni], acc[mi][ni], 0, 0, 0); \
      }                                                                        \
  }

// ---------- K1: MFMA GEMM1, all-register, barrier-free K-loop ----------
__global__ __launch_bounds__(256) void k_g1(
    const float* __restrict__ x, const float* __restrict__ stats,
    const _Float16* __restrict__ Pgh, const _Float16* __restrict__ Pgl,
    const float* __restrict__ gwv, const float* __restrict__ bwv,
    float* __restrict__ local_) {
  __shared__ float stage[32 * HID];   // 32 KB, epilogue only
  const int tid = threadIdx.x, lane = tid & 63, w = tid >> 6;
  const int kg = lane >> 4, lr = lane & 15;
  const int gr0 = blockIdx.x * 32;

  const float* asrc0 = x + (size_t)(gr0 + lr) * DIM + kg * 8;
  const float* asrc1 = x + (size_t)(gr0 + 16 + lr) * DIM + kg * 8;
  const _Float16* bh = Pgh + ((size_t)kg * 256 + w * 64 + lr) * 8;
  const _Float16* bl = Pgl + ((size_t)kg * 256 + w * 64 + lr) * 8;

  f32x4 acc[2][4];
  const f32x4 z4 = {0.f, 0.f, 0.f, 0.f};
  #pragma unroll
  for (int mi = 0; mi < 2; ++mi)
    #pragma unroll
    for (int ni = 0; ni < 4; ++ni) acc[mi][ni] = z4;
  float4 axv[2][4];
  f16x8 bxh[2][4], bxl[2][4];

  LOADA(asrc0, asrc1, 0, 0)
  LOADB(bh, bl, 0, 0)
  #pragma unroll
  for (int t = 0; t < 16; ++t) {
    const int pb = t & 1;
    if (t + 1 < 16) {
      LOADA(asrc0, asrc1, t + 1, pb ^ 1)
      LOADB(bh, bl, t + 1, pb ^ 1)
    }
    f16x8 fah[2], fal[2];
    SPLITA(pb, fah, fal)
    MFMA_CHUNK(pb, fah, fal)
  }

  // epilogue: LN fold + gelu -> LDS stage -> coalesced store
  float gwc[4], bwc[4];
  #pragma unroll
  for (int ni = 0; ni < 4; ++ni) {
    int col = w * 64 + ni * 16 + lr;
    gwc[ni] = gwv[col];
    bwc[ni] = bwv[col];
  }
  #pragma unroll
  for (int mi = 0; mi < 2; ++mi)
    #pragma unroll
    for (int i = 0; i < 4; ++i) {
      int rrel = mi * 16 + kg * 4 + i;
      int row = gr0 + rrel;
      float mn = stats[row * 2], rs = stats[row * 2 + 1];
      #pragma unroll
      for (int ni = 0; ni < 4; ++ni) {
        int col = w * 64 + ni * 16 + lr;
        float v = rs * acc[mi][ni][i] - rs * mn * gwc[ni] + bwc[ni];
        stage[rrel * HID + col] = gelu32(v);
      }
    }
  __syncthreads();
  {
    const float4* st4 = (const float4*)stage;
    float4* dst = (float4*)(local_ + (size_t)gr0 * HID);
    #pragma unroll
    for (int i = 0; i < 8; ++i) dst[tid + i * 256] = st4[tid + i * 256];
  }
}

// ---------- K2: MFMA GEMM2, all-register; epilogue -> scores ----------
__global__ __launch_bounds__(256) void k_g2(
    const float* __restrict__ local_,
    const _Float16* __restrict__ P1h, const _Float16* __restrict__ P1l,
    const float* __restrict__ W2, const float* __restrict__ c1,
    const float* __restrict__ c2, float* __restrict__ scores) {
  __shared__ float red1[32][4], red2[32][4];
  const int tid = threadIdx.x, lane = tid & 63, w = tid >> 6;
  const int kg = lane >> 4, lr = lane & 15;
  const int gr0 = blockIdx.x * 32;

  const float* asrc0 = local_ + (size_t)(gr0 + lr) * HID + kg * 8;
  const float* asrc1 = local_ + (size_t)(gr0 + 16 + lr) * HID + kg * 8;
  const _Float16* bh = P1h + ((size_t)kg * 256 + w * 64 + lr) * 8;
  const _Float16* bl = P1l + ((size_t)kg * 256 + w * 64 + lr) * 8;

  f32x4 acc[2][4];
  const f32x4 z4 = {0.f, 0.f, 0.f, 0.f};
  #pragma unroll
  for (int mi = 0; mi < 2; ++mi)
    #pragma unroll
    for (int ni = 0; ni < 4; ++ni) acc[mi][ni] = z4;
  float4 axv[2][4];
  f16x8 bxh[2][4], bxl[2][4];

  LOADA(asrc0, asrc1, 0, 0)
  LOADB(bh, bl, 0, 0)
  #pragma unroll
  for (int t = 0; t < 8; ++t) {
    const int pb = t & 1;
    if (t + 1 < 8) {
      LOADA(asrc0, asrc1, t + 1, pb ^ 1)
      LOADB(bh, bl, t + 1, pb ^ 1)
    }
    f16x8 fah[2], fal[2];
    SPLITA(pb, fah, fal)
    MFMA_CHUNK(pb, fah, fal)
  }

  float w2v[4];
  #pragma unroll
  for (int ni = 0; ni < 4; ++ni) w2v[ni] = W2[w * 64 + ni * 16 + lr];
  #pragma unroll
  for (int mi = 0; mi < 2; ++mi) {
    #pragma unroll
    for (int i = 0; i < 4; ++i) {
      int row = gr0 + mi * 16 + kg * 4 + i;
      int bf = row / NTOK;
      float p1 = 0.f, p2 = 0.f;
      #pragma unroll
      for (int ni = 0; ni < 4; ++ni) {
        int col = w * 64 + ni * 16 + lr;
        float u = acc[mi][ni][i];
        p1 = fmaf(gelu32(u + c1[(size_t)bf * HID + col]), w2v[ni], p1);
        p2 = fmaf(gelu32(u + c2[(size_t)bf * HID + col]), w2v[ni], p2);
      }
      #pragma unroll
      for (int m = 1; m < 16; m <<= 1) { p1 += __shfl_xor(p1, m); p2 += __shfl_xor(p2, m); }
      if (lr == 0) {
        red1[mi * 16 + kg * 4 + i][w] = p1;
        red2[mi * 16 + kg * 4 + i][w] = p2;
      }
    }
  }
  __syncthreads();
  if (tid < 32) {
    float s1 = red1[tid][0] + red1[tid][1] + red1[tid][2] + red1[tid][3];
    float s2 = red2[tid][0] + red2[tid][1] + red2[tid][2] + red2[tid][3];
    scores[gr0 + tid] = tanhf(s1) + tanhf(s2);
  }
}

// ---------- K3: perturbed top-k, tail-batched RNG, early-exit search ----------
__global__ __launch_bounds__(512) void k_topk(const float* __restrict__ scores,
                                              unsigned short* __restrict__ partial) {
  const int b = blockIdx.x, chunk = blockIdx.y;
  const int tid = threadIdx.x, lane = tid & 63, wv = tid >> 6;
  __shared__ float sc_s[NTOK];
  __shared__ int cnt_s[CNTSZ];
  if (tid < NTOK) sc_s[tid] = scores[b * NTOK + tid];
  for (int i = tid; i < CNTSZ; i += 512) cnt_s[i] = 0;

  const int s_first = chunk + SPB * wv;
  const unsigned gb = (unsigned)b * NS * 196u;

  float n_tail = 0.0f;
  {
    int si = lane >> 2, t = lane & 3;
    int s = s_first + si * (SPB * 8);
    if (lane < 28 && s < NS) {
      n_tail = noise_at(gb + (unsigned)s * 196u + 192u + (unsigned)t);
    }
  }
  __syncthreads();

  int si = 0;
  for (int s = s_first; s < NS; s += SPB * 8, ++si) {
    const unsigned gbase = gb + (unsigned)s * 196u;
    unsigned key[4];
    #pragma unroll
    for (int c = 0; c < 3; ++c) {
      float n = noise_at(gbase + (unsigned)(c * 64 + lane));
      float p = fmaf(0.05f, n, sc_s[c * 64 + lane]);
      unsigned ub = __float_as_uint(p);
      key[c] = (ub & 0x80000000u) ? ~ub : (ub | 0x80000000u);
    }
    {
      float n = __shfl(n_tail, si * 4 + (lane & 3));
      float p = fmaf(0.05f, n, sc_s[192 + (lane & 3)]);
      unsigned ub = __float_as_uint(p);
      unsigned k3 = (ub & 0x80000000u) ? ~ub : (ub | 0x80000000u);
      key[3] = (lane < 4) ? k3 : 0u;
    }
    unsigned prefix = 0u;
    bool exact = false;
    for (int bit = 31; bit >= 0; --bit) {
      unsigned t = prefix | (1u << bit);
      int cn = 0;
      #pragma unroll
      for (int c = 0; c < 4; ++c) cn += __popcll(__ballot(key[c] >= t));
      if (cn >= TOPK) {
        prefix = t;
        if (cn == TOPK) { exact = true; break; }
      }
    }
    unsigned long long lt = (1ull << lane) - 1ull;
    bool sel[4];
    if (exact) {
      #pragma unroll
      for (int c = 0; c < 4; ++c) sel[c] = key[c] >= prefix;
    } else {
      unsigned long long mE[4];
      int cntG = 0;
      #pragma unroll
      for (int c = 0; c < 4; ++c) {
        cntG += __popcll(__ballot(key[c] > prefix));
        mE[c] = __ballot(key[c] == prefix);
      }
      int need = TOPK - cntG;
      #pragma unroll
      for (int c = 0; c < 4; ++c) {
        int er = 0;
        for (int cc = 0; cc < c; ++cc) er += __popcll(mE[cc]);
        er += __popcll(mE[c] & lt);
        sel[c] = (key[c] > prefix) || ((key[c] == prefix) && (er < need));
      }
    }
    unsigned long long mS[4];
    #pragma unroll
    for (int c = 0; c < 4; ++c) mS[c] = __ballot(sel[c]);
    int base = 0;
    #pragma unroll
    for (int c = 0; c < 4; ++c) {
      if (sel[c]) {
        int rank = base + __popcll(mS[c] & lt);
        int j = c * 64 + lane;
        atomicAdd(&cnt_s[rank * NTOK + j], 1);
      }
      base += __popcll(mS[c]);
    }
  }
  __syncthreads();
  unsigned short* dst = partial + ((size_t)b * SPB + chunk) * CNTSZ;
  for (int i = tid; i < CNTSZ; i += 512) dst[i] = (unsigned short)cnt_s[i];
}

// ---------- K4: wsum[b][k][l] = (sum_c partial) / 500 ----------
__global__ __launch_bounds__(256) void k_sum(const unsigned short* __restrict__ partial,
                                             float* __restrict__ wsum) {
  int b = blockIdx.x;
  for (int i = blockIdx.y * 256 + threadIdx.x; i < CNTSZ; i += 8 * 256) {
    int c = 0;
    #pragma unroll
    for (int cc = 0; cc < SPB; ++cc)
      c += partial[((size_t)b * SPB + cc) * CNTSZ + i];
    wsum[(size_t)b * CNTSZ + i] = (float)c * 0.002f;
  }
}

// ---------- K5: out[b,k,dq*64+d] = sum_l wsum[b,k,l] * x[b,l,dq*64+d] ----------
// grid (96, 8): each block owns a disjoint 196x64 x-slice -> x read exactly once.
__global__ __launch_bounds__(256) void k_out(const float* __restrict__ x,
                                             const float* __restrict__ wsum,
                                             float* __restrict__ out) {
  const int b = blockIdx.x, dq = blockIdx.y;
  __shared__ float xs[NTOK][64];    // 50 KB
  __shared__ float wls[4][NTOK];    // 3.1 KB
  const int tid = threadIdx.x;

  // stage x slice (16 rows per pass, 256B contiguous per row)
  for (int r0 = 0; r0 < NTOK; r0 += 16) {
    int row = r0 + (tid >> 4);
    int c4 = (tid & 15) * 4;
    if (row < NTOK)
      *(float4*)&xs[row][c4] =
          *(const float4*)(x + ((size_t)(b * NTOK + row)) * DIM + dq * 64 + c4);
  }

  const int d = tid & 63, kq = tid >> 6;
  const float* wb = wsum + (size_t)b * CNTSZ;
  for (int kk = 0; kk < 13; ++kk) {
    __syncthreads();   // xs staged (first iter) / prior wls reads done
    for (int i = tid; i < 4 * NTOK; i += 256) {
      int q = i / NTOK, l = i - q * NTOK;
      int k2 = kk * 4 + q;
      wls[q][l] = (k2 < TOPK) ? wb[k2 * NTOK + l] : 0.0f;
    }
    __syncthreads();
    int k = kk * 4 + kq;
    if (k < TOPK) {
      float acc = 0.0f;
      for (int l = 0; l < NTOK; ++l) {
        float w = wls[kq][l];
        if (w != 0.0f) acc = fmaf(w, xs[l][d], acc);
      }
      out[((size_t)(b * TOPK + k)) * DIM + dq * 64 + d] = acc;
    }
  }
}

// ---------- launcher ----------
extern "C" void kernel_launch(void* const* d_in, const int* in_sizes, int n_in,
                              void* d_out, int out_size, void* d_ws, size_t ws_size,
                              hipStream_t stream) {
  const float* x       = (const float*)d_in[0];
  const float* gf      = (const float*)d_in[1];
  const float* gs      = (const float*)d_in[2];
  const float* ln_in_g = (const float*)d_in[3];
  const float* ln_in_b = (const float*)d_in[4];
  const float* W_in    = (const float*)d_in[5];
  const float* ln_gd_g = (const float*)d_in[6];
  const float* ln_gd_b = (const float*)d_in[7];
  const float* W_gd    = (const float*)d_in[8];
  const float* W_out1  = (const float*)d_in[9];
  const float* W_out2  = (const float*)d_in[10];
  float* out = (float*)d_out;

  // ws layout (~40 MB); wsum aliases local_ (dead after k_g2)
  char* p = (char*)d_ws;
  float* local_  = (float*)p;             p += (size_t)ROWS * HID * 4;          // 19.3 MB
  float* wsum    = local_;                                                      // alias
  unsigned short* partial = (unsigned short*)p; p += (size_t)BP * SPB * CNTSZ * 2; // 18.4 MB
  float* stats   = (float*)p;             p += (size_t)ROWS * 2 * 4;
  float* c1      = (float*)p;             p += (size_t)BP * HID * 4;
  float* c2      = (float*)p;             p += (size_t)BP * HID * 4;
  float* scores  = (float*)p;             p += (size_t)ROWS * 4;
  _Float16* Pgh  = (_Float16*)p;          p += (size_t)HID * DIM * 2;
  _Float16* Pgl  = (_Float16*)p;          p += (size_t)HID * DIM * 2;
  _Float16* P1h  = (_Float16*)p;          p += (size_t)HID * HID * 2;
  _Float16* P1l  = (_Float16*)p;          p += (size_t)HID * HID * 2;
  float* gwv     = (float*)p;             p += HID * 4;
  float* bwv     = (float*)p;             p += HID * 4;

  k_pre<<<PRE_GLOB + PRE_PREP + PRE_STATS, 256, 0, stream>>>(
      gf, gs, ln_gd_g, ln_gd_b, W_gd, W_out1, c1,
      W_in, ln_in_g, ln_in_b, Pgh, Pgl, P1h, P1l, gwv, bwv, x, stats);
  k_g1<<<GBLK, 256, 0, stream>>>(x, stats, Pgh, Pgl, gwv, bwv, local_);
  k_g2<<<GBLK, 256, 0, stream>>>(local_, P1h, P1l, W_out2, c1, c2, scores);
  k_topk<<<dim3(BP, SPB), 512, 0, stream>>>(scores, partial);
  k_sum<<<dim3(BP, 8), 256, 0, stream>>>(partial, wsum);
  k_out<<<dim3(BP, 8), 256, 0, stream>>>(x, wsum, out);
}

// Round 18
// 167.823 us; speedup vs baseline: 1.7994x; 1.7994x over previous
//
#include <hip/hip_runtime.h>
#include <stdint.h>

#define DEV __device__ __forceinline__

// ---------- problem constants ----------
#define BP 96
#define NTOK 196
#define DIM 512
#define HID 256
#define NS 500
#define TOPK 49
#define ROWS (BP * NTOK)          // 18816
#define GBLK (ROWS / 32)          // 588 blocks for MFMA GEMMs
#define SPB 10                    // sample-chunks per frame-batch
#define CNTSZ (TOPK * NTOK)       // 9604

typedef _Float16 f16x8 __attribute__((ext_vector_type(8)));
typedef float f32x4 __attribute__((ext_vector_type(4)));

// ---------- math helpers ----------
DEV float gelu32(float v) {
  return 0.5f * v * (1.0f + erff(v * 0.70710678f));
}

// Threefry-2x32, 20 rounds, key = (0, 1)  (jax.random.key(1))
DEV void threefry2x32(uint32_t x0, uint32_t x1, uint32_t& o0, uint32_t& o1) {
  const uint32_t k0 = 0u, k1 = 1u;
  const uint32_t k2 = 0x1BD11BDAu ^ k0 ^ k1;
  x0 += k0; x1 += k1;
#define TF_R(r) { x0 += x1; x1 = (x1 << (r)) | (x1 >> (32 - (r))); x1 ^= x0; }
  TF_R(13) TF_R(15) TF_R(26) TF_R(6)
  x0 += k1; x1 += k2 + 1u;
  TF_R(17) TF_R(29) TF_R(16) TF_R(24)
  x0 += k2; x1 += k0 + 2u;
  TF_R(13) TF_R(15) TF_R(26) TF_R(6)
  x0 += k0; x1 += k1 + 3u;
  TF_R(17) TF_R(29) TF_R(16) TF_R(24)
  x0 += k1; x1 += k2 + 4u;
  TF_R(13) TF_R(15) TF_R(26) TF_R(6)
  x0 += k2; x1 += k0 + 5u;
#undef TF_R
  o0 = x0; o1 = x1;
}

// XLA ErfInv32 (Giles polynomial). w via native v_log_f32 (flip-safe, r13-proven)
DEV float erfinv_xla(float x) {
  float w = -__logf(fmaf(-x, x, 1.0f));
  float ws = w - 2.5f;
  float ps = 2.81022636e-08f;
  ps = fmaf(ps, ws, 3.43273939e-07f);
  ps = fmaf(ps, ws, -3.5233877e-06f);
  ps = fmaf(ps, ws, -4.39150654e-06f);
  ps = fmaf(ps, ws, 0.00021858087f);
  ps = fmaf(ps, ws, -0.00125372503f);
  ps = fmaf(ps, ws, -0.00417768164f);
  ps = fmaf(ps, ws, 0.246640727f);
  ps = fmaf(ps, ws, 1.50140941f);
  float r = ps;
  if (__ballot(w >= 5.0f) != 0ull) {
    float wl = sqrtf(w) - 3.0f;
    float pl = -0.000200214257f;
    pl = fmaf(pl, wl, 0.000100950558f);
    pl = fmaf(pl, wl, 0.00134934322f);
    pl = fmaf(pl, wl, -0.00367342844f);
    pl = fmaf(pl, wl, 0.00573950773f);
    pl = fmaf(pl, wl, -0.0076224613f);
    pl = fmaf(pl, wl, 0.00943887047f);
    pl = fmaf(pl, wl, 1.00167406f);
    pl = fmaf(pl, wl, 2.83297682f);
    r = (w < 5.0f) ? ps : pl;
  }
  return r * x;
}

// jax-f32-faithful N(0,1) noise, PARTITIONABLE threefry: counter=(0,g), draw=o0^o1
DEV float noise_at(unsigned g) {
  unsigned o0, o1;
  threefry2x32(0u, g, o0, o1);
  unsigned bits = o0 ^ o1;
  float f = __uint_as_float((bits >> 9) | 0x3f800000u) - 1.0f;
  float u = f * 2.0f - 0.99999994f;
  u = fmaxf(-0.99999994f, u);
  return 1.41421356f * erfinv_xla(u);
}

// fragment-major weight packing: P[((t*4+kg)*256 + col)*8 + e] = W[k=t*32+kg*8+e][col]
DEV size_t pack_idx(int k, int col) {
  int t = k >> 5, kg = (k >> 3) & 3, e = k & 7;
  return (((size_t)(t * 4 + kg) * 256) + col) * 8 + e;
}

// ---------- K0: merged pre-pass: glob (192) | wprep (512) | stats (4704) ----------
#define PRE_GLOB 192
#define PRE_PREP 512
#define PRE_STATS (ROWS / 4)
__global__ __launch_bounds__(256) void k_pre(
    const float* __restrict__ gf, const float* __restrict__ gs,
    const float* __restrict__ lng, const float* __restrict__ lnb,
    const float* __restrict__ Wgd, const float* __restrict__ Wout1,
    float* __restrict__ cout,
    const float* __restrict__ Win,
    const float* __restrict__ g_in, const float* __restrict__ b_in,
    _Float16* __restrict__ Pgh, _Float16* __restrict__ Pgl,
    _Float16* __restrict__ P1h, _Float16* __restrict__ P1l,
    float* __restrict__ gwv, float* __restrict__ bwv,
    const float* __restrict__ x, float* __restrict__ stats) {
  const int bid = blockIdx.x;
  if (bid < PRE_GLOB) {
    int bq = bid >> 1, which = bid & 1;
    const float* row = which ? (gs + (size_t)(bq / 12) * DIM) : (gf + (size_t)bq * DIM);
    __shared__ float lx[DIM];
    __shared__ float sg[HID];
    __shared__ double sred[8];
    int tid = threadIdx.x, lane = tid & 63, wv = tid >> 6;
    float v0 = row[tid], v1 = row[tid + 256];
    double s = (double)v0 + v1, q = (double)v0 * v0 + (double)v1 * v1;
    #pragma unroll
    for (int m = 1; m < 64; m <<= 1) { s += __shfl_xor(s, m); q += __shfl_xor(q, m); }
    if (lane == 0) { sred[wv * 2] = s; sred[wv * 2 + 1] = q; }
    __syncthreads();
    double ts = sred[0] + sred[2] + sred[4] + sred[6];
    double tq = sred[1] + sred[3] + sred[5] + sred[7];
    double mean = ts / 512.0;
    double var = tq / 512.0 - mean * mean;
    float mn = (float)mean;
    float rs = (float)(1.0 / sqrt(var + 1e-5));
    lx[tid]       = (v0 - mn) * rs * lng[tid] + lnb[tid];
    lx[tid + 256] = (v1 - mn) * rs * lng[tid + 256] + lnb[tid + 256];
    __syncthreads();
    float acc = 0.0f;
    for (int d = 0; d < DIM; ++d) acc = fmaf(lx[d], Wgd[(size_t)d * HID + tid], acc);
    sg[tid] = gelu32(acc);
    __syncthreads();
    float c = 0.0f;
    for (int j = 0; j < HID; ++j) c = fmaf(sg[j], Wout1[(size_t)(HID + j) * HID + tid], c);
    cout[((size_t)which * BP + bq) * HID + tid] = c;
  } else if (bid < PRE_GLOB + PRE_PREP) {
    int b2 = bid - PRE_GLOB;
    int n = b2 & 255, half = b2 >> 8;
    if (half == 0) {
      __shared__ float wred[8];
      int tid = threadIdx.x, lane = tid & 63, wv = tid >> 6;
      float sgv = 0.0f, sbv = 0.0f;
      #pragma unroll
      for (int kk = 0; kk < 2; ++kk) {
        int k = tid + kk * 256;
        float w = Win[(size_t)k * HID + n];
        float wg = w * g_in[k];
        _Float16 h = (_Float16)wg;
        size_t pi = pack_idx(k, n);
        Pgh[pi] = h;
        Pgl[pi] = (_Float16)(wg - (float)h);
        sgv += wg;
        sbv = fmaf(b_in[k], w, sbv);
      }
      #pragma unroll
      for (int m = 1; m < 64; m <<= 1) { sgv += __shfl_xor(sgv, m); sbv += __shfl_xor(sbv, m); }
      if (lane == 0) { wred[wv * 2] = sgv; wred[wv * 2 + 1] = sbv; }
      __syncthreads();
      if (tid == 0) {
        gwv[n] = wred[0] + wred[2] + wred[4] + wred[6];
        bwv[n] = wred[1] + wred[3] + wred[5] + wred[7];
      }
    } else {
      int k = threadIdx.x;
      float v = Wout1[(size_t)k * HID + n];
      _Float16 h = (_Float16)v;
      size_t pi = pack_idx(k, n);
      P1h[pi] = h;
      P1l[pi] = (_Float16)(v - (float)h);
    }
  } else {
    int r = (bid - PRE_GLOB - PRE_PREP) * 4 + (threadIdx.x >> 6);
    int lane = threadIdx.x & 63;
    const float4* xr = (const float4*)(x + (size_t)r * DIM);
    float4 a = xr[lane], c = xr[lane + 64];
    double s = (double)a.x + a.y + a.z + a.w + (double)c.x + c.y + c.z + c.w;
    double q = (double)a.x * a.x + (double)a.y * a.y + (double)a.z * a.z + (double)a.w * a.w +
               (double)c.x * c.x + (double)c.y * c.y + (double)c.z * c.z + (double)c.w * c.w;
    #pragma unroll
    for (int m = 1; m < 64; m <<= 1) { s += __shfl_xor(s, m); q += __shfl_xor(q, m); }
    if (lane == 0) {
      double mean = s / 512.0;
      double var = q / 512.0 - mean * mean;
      stats[r * 2]     = (float)mean;
      stats[r * 2 + 1] = (float)(1.0 / sqrt(var + 1e-5));
    }
  }
}

// ---------- shared GEMM machinery: all-register, no LDS in loop ----------
#define LOADA(src0, src1, t, pb)                                               \
  {                                                                            \
    axv[pb][0] = *(const float4*)((src0) + (t) * 32);                          \
    axv[pb][1] = *(const float4*)((src0) + (t) * 32 + 4);                      \
    axv[pb][2] = *(const float4*)((src1) + (t) * 32);                          \
    axv[pb][3] = *(const float4*)((src1) + (t) * 32 + 4);                      \
  }

#define LOADB(bh, bl, t, pb)                                                   \
  {                                                                            \
    _Pragma("unroll")                                                          \
    for (int ni = 0; ni < 4; ++ni) {                                           \
      bxh[pb][ni] = *(const f16x8*)((bh) + (size_t)(t) * 8192 + ni * 128);     \
      bxl[pb][ni] = *(const f16x8*)((bl) + (size_t)(t) * 8192 + ni * 128);     \
    }                                                                          \
  }

#define SPLITA(pb, fah, fal)                                                   \
  {                                                                            \
    _Pragma("unroll")                                                          \
    for (int mi = 0; mi < 2; ++mi) {                                           \
      float va[8];                                                             \
      *(float4*)&va[0] = axv[pb][mi * 2];                                      \
      *(float4*)&va[4] = axv[pb][mi * 2 + 1];                                  \
      _Pragma("unroll")                                                        \
      for (int e = 0; e < 8; ++e) {                                            \
        _Float16 h = (_Float16)va[e];                                          \
        fah[mi][e] = h;                                                        \
        fal[mi][e] = (_Float16)(va[e] - (float)h);                             \
      }                                                                        \
    }                                                                          \
  }

#define MFMA_CHUNK(pb, fah, fal)                                               \
  {                                                                            \
    _Pragma("unroll")                                                          \
    for (int mi = 0; mi < 2; ++mi)                                             \
      _Pragma("unroll")                                                        \
      for (int ni = 0; ni < 4; ++ni) {                                         \
        acc[mi][ni] = __builtin_amdgcn_mfma_f32_16x16x32_f16(fah[mi], bxh[pb][ni], acc[mi][ni], 0, 0, 0); \
        acc[mi][ni] = __builtin_amdgcn_mfma_f32_16x16x32_f16(fah[mi], bxl[pb][ni], acc[mi][ni], 0, 0, 0); \
        acc[mi][ni] = __builtin_amdgcn_mfma_f32_16x16x32_f16(fal[mi], bxh[pb][ni], acc[mi][ni], 0, 0, 0); \
      }                                                                        \
  }

// ---------- K1: MFMA GEMM1, all-register, barrier-free K-loop ----------
__global__ __launch_bounds__(256) void k_g1(
    const float* __restrict__ x, const float* __restrict__ stats,
    const _Float16* __restrict__ Pgh, const _Float16* __restrict__ Pgl,
    const float* __restrict__ gwv, const float* __restrict__ bwv,
    float* __restrict__ local_) {
  __shared__ float stage[32 * HID];   // 32 KB, epilogue only
  const int tid = threadIdx.x, lane = tid & 63, w = tid >> 6;
  const int kg = lane >> 4, lr = lane & 15;
  const int gr0 = blockIdx.x * 32;

  const float* asrc0 = x + (size_t)(gr0 + lr) * DIM + kg * 8;
  const float* asrc1 = x + (size_t)(gr0 + 16 + lr) * DIM + kg * 8;
  const _Float16* bh = Pgh + ((size_t)kg * 256 + w * 64 + lr) * 8;
  const _Float16* bl = Pgl + ((size_t)kg * 256 + w * 64 + lr) * 8;

  f32x4 acc[2][4];
  const f32x4 z4 = {0.f, 0.f, 0.f, 0.f};
  #pragma unroll
  for (int mi = 0; mi < 2; ++mi)
    #pragma unroll
    for (int ni = 0; ni < 4; ++ni) acc[mi][ni] = z4;
  float4 axv[2][4];
  f16x8 bxh[2][4], bxl[2][4];

  LOADA(asrc0, asrc1, 0, 0)
  LOADB(bh, bl, 0, 0)
  #pragma unroll
  for (int t = 0; t < 16; ++t) {
    const int pb = t & 1;
    if (t + 1 < 16) {
      LOADA(asrc0, asrc1, t + 1, pb ^ 1)
      LOADB(bh, bl, t + 1, pb ^ 1)
    }
    f16x8 fah[2], fal[2];
    SPLITA(pb, fah, fal)
    MFMA_CHUNK(pb, fah, fal)
  }

  // epilogue: LN fold + gelu -> LDS stage -> coalesced store
  float gwc[4], bwc[4];
  #pragma unroll
  for (int ni = 0; ni < 4; ++ni) {
    int col = w * 64 + ni * 16 + lr;
    gwc[ni] = gwv[col];
    bwc[ni] = bwv[col];
  }
  #pragma unroll
  for (int mi = 0; mi < 2; ++mi)
    #pragma unroll
    for (int i = 0; i < 4; ++i) {
      int rrel = mi * 16 + kg * 4 + i;
      int row = gr0 + rrel;
      float mn = stats[row * 2], rs = stats[row * 2 + 1];
      #pragma unroll
      for (int ni = 0; ni < 4; ++ni) {
        int col = w * 64 + ni * 16 + lr;
        float v = rs * acc[mi][ni][i] - rs * mn * gwc[ni] + bwc[ni];
        stage[rrel * HID + col] = gelu32(v);
      }
    }
  __syncthreads();
  {
    const float4* st4 = (const float4*)stage;
    float4* dst = (float4*)(local_ + (size_t)gr0 * HID);
    #pragma unroll
    for (int i = 0; i < 8; ++i) dst[tid + i * 256] = st4[tid + i * 256];
  }
}

// ---------- K2: MFMA GEMM2, all-register; epilogue -> scores ----------
__global__ __launch_bounds__(256) void k_g2(
    const float* __restrict__ local_,
    const _Float16* __restrict__ P1h, const _Float16* __restrict__ P1l,
    const float* __restrict__ W2, const float* __restrict__ c1,
    const float* __restrict__ c2, float* __restrict__ scores) {
  __shared__ float red1[32][4], red2[32][4];
  const int tid = threadIdx.x, lane = tid & 63, w = tid >> 6;
  const int kg = lane >> 4, lr = lane & 15;
  const int gr0 = blockIdx.x * 32;

  const float* asrc0 = local_ + (size_t)(gr0 + lr) * HID + kg * 8;
  const float* asrc1 = local_ + (size_t)(gr0 + 16 + lr) * HID + kg * 8;
  const _Float16* bh = P1h + ((size_t)kg * 256 + w * 64 + lr) * 8;
  const _Float16* bl = P1l + ((size_t)kg * 256 + w * 64 + lr) * 8;

  f32x4 acc[2][4];
  const f32x4 z4 = {0.f, 0.f, 0.f, 0.f};
  #pragma unroll
  for (int mi = 0; mi < 2; ++mi)
    #pragma unroll
    for (int ni = 0; ni < 4; ++ni) acc[mi][ni] = z4;
  float4 axv[2][4];
  f16x8 bxh[2][4], bxl[2][4];

  LOADA(asrc0, asrc1, 0, 0)
  LOADB(bh, bl, 0, 0)
  #pragma unroll
  for (int t = 0; t < 8; ++t) {
    const int pb = t & 1;
    if (t + 1 < 8) {
      LOADA(asrc0, asrc1, t + 1, pb ^ 1)
      LOADB(bh, bl, t + 1, pb ^ 1)
    }
    f16x8 fah[2], fal[2];
    SPLITA(pb, fah, fal)
    MFMA_CHUNK(pb, fah, fal)
  }

  float w2v[4];
  #pragma unroll
  for (int ni = 0; ni < 4; ++ni) w2v[ni] = W2[w * 64 + ni * 16 + lr];
  #pragma unroll
  for (int mi = 0; mi < 2; ++mi) {
    #pragma unroll
    for (int i = 0; i < 4; ++i) {
      int row = gr0 + mi * 16 + kg * 4 + i;
      int bf = row / NTOK;
      float p1 = 0.f, p2 = 0.f;
      #pragma unroll
      for (int ni = 0; ni < 4; ++ni) {
        int col = w * 64 + ni * 16 + lr;
        float u = acc[mi][ni][i];
        p1 = fmaf(gelu32(u + c1[(size_t)bf * HID + col]), w2v[ni], p1);
        p2 = fmaf(gelu32(u + c2[(size_t)bf * HID + col]), w2v[ni], p2);
      }
      #pragma unroll
      for (int m = 1; m < 16; m <<= 1) { p1 += __shfl_xor(p1, m); p2 += __shfl_xor(p2, m); }
      if (lr == 0) {
        red1[mi * 16 + kg * 4 + i][w] = p1;
        red2[mi * 16 + kg * 4 + i][w] = p2;
      }
    }
  }
  __syncthreads();
  if (tid < 32) {
    float s1 = red1[tid][0] + red1[tid][1] + red1[tid][2] + red1[tid][3];
    float s2 = red2[tid][0] + red2[tid][1] + red2[tid][2] + red2[tid][3];
    scores[gr0 + tid] = tanhf(s1) + tanhf(s2);
  }
}

// ---------- K3: perturbed top-k, tail-batched RNG, early-exit search ----------
__global__ __launch_bounds__(512) void k_topk(const float* __restrict__ scores,
                                              unsigned short* __restrict__ partial) {
  const int b = blockIdx.x, chunk = blockIdx.y;
  const int tid = threadIdx.x, lane = tid & 63, wv = tid >> 6;
  __shared__ float sc_s[NTOK];
  __shared__ int cnt_s[CNTSZ];
  if (tid < NTOK) sc_s[tid] = scores[b * NTOK + tid];
  for (int i = tid; i < CNTSZ; i += 512) cnt_s[i] = 0;

  const int s_first = chunk + SPB * wv;
  const unsigned gb = (unsigned)b * NS * 196u;

  float n_tail = 0.0f;
  {
    int si = lane >> 2, t = lane & 3;
    int s = s_first + si * (SPB * 8);
    if (lane < 28 && s < NS) {
      n_tail = noise_at(gb + (unsigned)s * 196u + 192u + (unsigned)t);
    }
  }
  __syncthreads();

  int si = 0;
  for (int s = s_first; s < NS; s += SPB * 8, ++si) {
    const unsigned gbase = gb + (unsigned)s * 196u;
    unsigned key[4];
    #pragma unroll
    for (int c = 0; c < 3; ++c) {
      float n = noise_at(gbase + (unsigned)(c * 64 + lane));
      float p = fmaf(0.05f, n, sc_s[c * 64 + lane]);
      unsigned ub = __float_as_uint(p);
      key[c] = (ub & 0x80000000u) ? ~ub : (ub | 0x80000000u);
    }
    {
      float n = __shfl(n_tail, si * 4 + (lane & 3));
      float p = fmaf(0.05f, n, sc_s[192 + (lane & 3)]);
      unsigned ub = __float_as_uint(p);
      unsigned k3 = (ub & 0x80000000u) ? ~ub : (ub | 0x80000000u);
      key[3] = (lane < 4) ? k3 : 0u;
    }
    unsigned prefix = 0u;
    bool exact = false;
    for (int bit = 31; bit >= 0; --bit) {
      unsigned t = prefix | (1u << bit);
      int cn = 0;
      #pragma unroll
      for (int c = 0; c < 4; ++c) cn += __popcll(__ballot(key[c] >= t));
      if (cn >= TOPK) {
        prefix = t;
        if (cn == TOPK) { exact = true; break; }
      }
    }
    unsigned long long lt = (1ull << lane) - 1ull;
    bool sel[4];
    if (exact) {
      #pragma unroll
      for (int c = 0; c < 4; ++c) sel[c] = key[c] >= prefix;
    } else {
      unsigned long long mE[4];
      int cntG = 0;
      #pragma unroll
      for (int c = 0; c < 4; ++c) {
        cntG += __popcll(__ballot(key[c] > prefix));
        mE[c] = __ballot(key[c] == prefix);
      }
      int need = TOPK - cntG;
      #pragma unroll
      for (int c = 0; c < 4; ++c) {
        int er = 0;
        for (int cc = 0; cc < c; ++cc) er += __popcll(mE[cc]);
        er += __popcll(mE[c] & lt);
        sel[c] = (key[c] > prefix) || ((key[c] == prefix) && (er < need));
      }
    }
    unsigned long long mS[4];
    #pragma unroll
    for (int c = 0; c < 4; ++c) mS[c] = __ballot(sel[c]);
    int base = 0;
    #pragma unroll
    for (int c = 0; c < 4; ++c) {
      if (sel[c]) {
        int rank = base + __popcll(mS[c] & lt);
        int j = c * 64 + lane;
        atomicAdd(&cnt_s[rank * NTOK + j], 1);
      }
      base += __popcll(mS[c]);
    }
  }
  __syncthreads();
  unsigned short* dst = partial + ((size_t)b * SPB + chunk) * CNTSZ;
  for (int i = tid; i < CNTSZ; i += 512) dst[i] = (unsigned short)cnt_s[i];
}

// ---------- K4: out[b,k,:] = sum_l (sum_c partial)/500 * x[b,l,:] ----------
// grid transposed: bid = k*BP + b  ->  all 49 blocks of frame b share bid%8
// (same XCD L2) so x[b]'s 400KB slice is fetched from HBM once, not 8x.
__global__ __launch_bounds__(256) void k_out(const float* __restrict__ x,
                                             const unsigned short* __restrict__ partial,
                                             float* __restrict__ out) {
  int bid = blockIdx.x;
  int b = bid % BP, k = bid / BP;
  __shared__ float swv[NTOK];
  __shared__ int idxs[NTOK];
  __shared__ int wcnt[4];
  __shared__ int wbase[5];
  __shared__ float4 part2[128];
  const int tid = threadIdx.x, lane = tid & 63, wv = tid >> 6;

  int cval = 0;
  if (tid < NTOK) {
    #pragma unroll
    for (int cc = 0; cc < SPB; ++cc)
      cval += partial[((size_t)b * SPB + cc) * CNTSZ + k * NTOK + tid];
  }
  unsigned long long m = __ballot(cval != 0);
  if (lane == 0) wcnt[wv] = __popcll(m);
  __syncthreads();
  if (tid == 0) {
    int a = 0;
    #pragma unroll
    for (int i = 0; i < 4; ++i) { wbase[i] = a; a += wcnt[i]; }
    wbase[4] = a;
  }
  __syncthreads();
  if (cval != 0) {
    int pos = wbase[wv] + __popcll(m & ((1ull << lane) - 1ull));
    idxs[pos] = tid;
    swv[pos] = (float)cval * 0.002f;
  }
  __syncthreads();
  const int n = wbase[4];
  const int half = tid >> 7, d4 = tid & 127;
  const int i0 = half ? (n + 1) / 2 : 0;
  const int i1 = half ? n : (n + 1) / 2;
  float a0 = 0, a1 = 0, a2 = 0, a3 = 0;
  for (int i = i0; i < i1; ++i) {
    float w = swv[i];
    float4 xv = *(const float4*)(x + ((size_t)(b * NTOK + idxs[i])) * DIM + d4 * 4);
    a0 = fmaf(w, xv.x, a0); a1 = fmaf(w, xv.y, a1);
    a2 = fmaf(w, xv.z, a2); a3 = fmaf(w, xv.w, a3);
  }
  if (half == 1) part2[d4] = make_float4(a0, a1, a2, a3);
  __syncthreads();
  if (half == 0) {
    float4 p = part2[d4];
    float4 o = make_float4(a0 + p.x, a1 + p.y, a2 + p.z, a3 + p.w);
    *(float4*)(out + ((size_t)(b * TOPK + k)) * DIM + d4 * 4) = o;
  }
}

// ---------- launcher ----------
extern "C" void kernel_launch(void* const* d_in, const int* in_sizes, int n_in,
                              void* d_out, int out_size, void* d_ws, size_t ws_size,
                              hipStream_t stream) {
  const float* x       = (const float*)d_in[0];
  const float* gf      = (const float*)d_in[1];
  const float* gs      = (const float*)d_in[2];
  const float* ln_in_g = (const float*)d_in[3];
  const float* ln_in_b = (const float*)d_in[4];
  const float* W_in    = (const float*)d_in[5];
  const float* ln_gd_g = (const float*)d_in[6];
  const float* ln_gd_b = (const float*)d_in[7];
  const float* W_gd    = (const float*)d_in[8];
  const float* W_out1  = (const float*)d_in[9];
  const float* W_out2  = (const float*)d_in[10];
  float* out = (float*)d_out;

  // ws layout (~40 MB)
  char* p = (char*)d_ws;
  float* local_  = (float*)p;             p += (size_t)ROWS * HID * 4;          // 19.3 MB
  unsigned short* partial = (unsigned short*)p; p += (size_t)BP * SPB * CNTSZ * 2; // 18.4 MB
  float* stats   = (float*)p;             p += (size_t)ROWS * 2 * 4;
  float* c1      = (float*)p;             p += (size_t)BP * HID * 4;
  float* c2      = (float*)p;             p += (size_t)BP * HID * 4;
  float* scores  = (float*)p;             p += (size_t)ROWS * 4;
  _Float16* Pgh  = (_Float16*)p;          p += (size_t)HID * DIM * 2;
  _Float16* Pgl  = (_Float16*)p;          p += (size_t)HID * DIM * 2;
  _Float16* P1h  = (_Float16*)p;          p += (size_t)HID * HID * 2;
  _Float16* P1l  = (_Float16*)p;          p += (size_t)HID * HID * 2;
  float* gwv     = (float*)p;             p += HID * 4;
  float* bwv     = (float*)p;             p += HID * 4;

  k_pre<<<PRE_GLOB + PRE_PREP + PRE_STATS, 256, 0, stream>>>(
      gf, gs, ln_gd_g, ln_gd_b, W_gd, W_out1, c1,
      W_in, ln_in_g, ln_in_b, Pgh, Pgl, P1h, P1l, gwv, bwv, x, stats);
  k_g1<<<GBLK, 256, 0, stream>>>(x, stats, Pgh, Pgl, gwv, bwv, local_);
  k_g2<<<GBLK, 256, 0, stream>>>(local_, P1h, P1l, W_out2, c1, c2, scores);
  k_topk<<<dim3(BP, SPB), 512, 0, stream>>>(scores, partial);
  k_out<<<BP * TOPK, 256, 0, stream>>>(x, partial, out);
}

// Round 19
// 154.821 us; speedup vs baseline: 1.9505x; 1.0840x over previous
//
#include <hip/hip_runtime.h>
#include <stdint.h>

#define DEV __device__ __forceinline__

// ---------- problem constants ----------
#define BP 96
#define NTOK 196
#define DIM 512
#define HID 256
#define NS 500
#define TOPK 49
#define ROWS (BP * NTOK)          // 18816
#define GBLK (ROWS / 32)          // 588 blocks for the fused MFMA GEMM
#define SPB 10                    // sample-chunks per frame-batch
#define CNTSZ (TOPK * NTOK)       // 9604
#define SPAD 260                  // stage row stride (floats): 2-way write, 8-way read

typedef _Float16 f16x8 __attribute__((ext_vector_type(8)));
typedef float f32x4 __attribute__((ext_vector_type(4)));

// ---------- math helpers ----------
DEV float gelu32(float v) {
  return 0.5f * v * (1.0f + erff(v * 0.70710678f));
}

// Threefry-2x32, 20 rounds, key = (0, 1)  (jax.random.key(1))
DEV void threefry2x32(uint32_t x0, uint32_t x1, uint32_t& o0, uint32_t& o1) {
  const uint32_t k0 = 0u, k1 = 1u;
  const uint32_t k2 = 0x1BD11BDAu ^ k0 ^ k1;
  x0 += k0; x1 += k1;
#define TF_R(r) { x0 += x1; x1 = (x1 << (r)) | (x1 >> (32 - (r))); x1 ^= x0; }
  TF_R(13) TF_R(15) TF_R(26) TF_R(6)
  x0 += k1; x1 += k2 + 1u;
  TF_R(17) TF_R(29) TF_R(16) TF_R(24)
  x0 += k2; x1 += k0 + 2u;
  TF_R(13) TF_R(15) TF_R(26) TF_R(6)
  x0 += k0; x1 += k1 + 3u;
  TF_R(17) TF_R(29) TF_R(16) TF_R(24)
  x0 += k1; x1 += k2 + 4u;
  TF_R(13) TF_R(15) TF_R(26) TF_R(6)
  x0 += k2; x1 += k0 + 5u;
#undef TF_R
  o0 = x0; o1 = x1;
}

// XLA ErfInv32 (Giles polynomial). w via native v_log_f32 (flip-safe, r13-proven)
DEV float erfinv_xla(float x) {
  float w = -__logf(fmaf(-x, x, 1.0f));
  float ws = w - 2.5f;
  float ps = 2.81022636e-08f;
  ps = fmaf(ps, ws, 3.43273939e-07f);
  ps = fmaf(ps, ws, -3.5233877e-06f);
  ps = fmaf(ps, ws, -4.39150654e-06f);
  ps = fmaf(ps, ws, 0.00021858087f);
  ps = fmaf(ps, ws, -0.00125372503f);
  ps = fmaf(ps, ws, -0.00417768164f);
  ps = fmaf(ps, ws, 0.246640727f);
  ps = fmaf(ps, ws, 1.50140941f);
  float r = ps;
  if (__ballot(w >= 5.0f) != 0ull) {
    float wl = sqrtf(w) - 3.0f;
    float pl = -0.000200214257f;
    pl = fmaf(pl, wl, 0.000100950558f);
    pl = fmaf(pl, wl, 0.00134934322f);
    pl = fmaf(pl, wl, -0.00367342844f);
    pl = fmaf(pl, wl, 0.00573950773f);
    pl = fmaf(pl, wl, -0.0076224613f);
    pl = fmaf(pl, wl, 0.00943887047f);
    pl = fmaf(pl, wl, 1.00167406f);
    pl = fmaf(pl, wl, 2.83297682f);
    r = (w < 5.0f) ? ps : pl;
  }
  return r * x;
}

// jax-f32-faithful N(0,1) noise, PARTITIONABLE threefry: counter=(0,g), draw=o0^o1
DEV float noise_at(unsigned g) {
  unsigned o0, o1;
  threefry2x32(0u, g, o0, o1);
  unsigned bits = o0 ^ o1;
  float f = __uint_as_float((bits >> 9) | 0x3f800000u) - 1.0f;
  float u = f * 2.0f - 0.99999994f;
  u = fmaxf(-0.99999994f, u);
  return 1.41421356f * erfinv_xla(u);
}

// fragment-major weight packing: P[((t*4+kg)*256 + col)*8 + e] = W[k=t*32+kg*8+e][col]
DEV size_t pack_idx(int k, int col) {
  int t = k >> 5, kg = (k >> 3) & 3, e = k & 7;
  return (((size_t)(t * 4 + kg) * 256) + col) * 8 + e;
}

// ---------- K0: merged pre-pass: glob (192) | wprep (512) | stats (4704) ----------
#define PRE_GLOB 192
#define PRE_PREP 512
#define PRE_STATS (ROWS / 4)
__global__ __launch_bounds__(256) void k_pre(
    const float* __restrict__ gf, const float* __restrict__ gs,
    const float* __restrict__ lng, const float* __restrict__ lnb,
    const float* __restrict__ Wgd, const float* __restrict__ Wout1,
    float* __restrict__ cout,
    const float* __restrict__ Win,
    const float* __restrict__ g_in, const float* __restrict__ b_in,
    _Float16* __restrict__ Pgh, _Float16* __restrict__ Pgl,
    _Float16* __restrict__ P1h, _Float16* __restrict__ P1l,
    float* __restrict__ gwv, float* __restrict__ bwv,
    const float* __restrict__ x, float* __restrict__ stats) {
  const int bid = blockIdx.x;
  if (bid < PRE_GLOB) {
    int bq = bid >> 1, which = bid & 1;
    const float* row = which ? (gs + (size_t)(bq / 12) * DIM) : (gf + (size_t)bq * DIM);
    __shared__ float lx[DIM];
    __shared__ float sg[HID];
    __shared__ double sred[8];
    int tid = threadIdx.x, lane = tid & 63, wv = tid >> 6;
    float v0 = row[tid], v1 = row[tid + 256];
    double s = (double)v0 + v1, q = (double)v0 * v0 + (double)v1 * v1;
    #pragma unroll
    for (int m = 1; m < 64; m <<= 1) { s += __shfl_xor(s, m); q += __shfl_xor(q, m); }
    if (lane == 0) { sred[wv * 2] = s; sred[wv * 2 + 1] = q; }
    __syncthreads();
    double ts = sred[0] + sred[2] + sred[4] + sred[6];
    double tq = sred[1] + sred[3] + sred[5] + sred[7];
    double mean = ts / 512.0;
    double var = tq / 512.0 - mean * mean;
    float mn = (float)mean;
    float rs = (float)(1.0 / sqrt(var + 1e-5));
    lx[tid]       = (v0 - mn) * rs * lng[tid] + lnb[tid];
    lx[tid + 256] = (v1 - mn) * rs * lng[tid + 256] + lnb[tid + 256];
    __syncthreads();
    float acc = 0.0f;
    for (int d = 0; d < DIM; ++d) acc = fmaf(lx[d], Wgd[(size_t)d * HID + tid], acc);
    sg[tid] = gelu32(acc);
    __syncthreads();
    float c = 0.0f;
    for (int j = 0; j < HID; ++j) c = fmaf(sg[j], Wout1[(size_t)(HID + j) * HID + tid], c);
    cout[((size_t)which * BP + bq) * HID + tid] = c;
  } else if (bid < PRE_GLOB + PRE_PREP) {
    int b2 = bid - PRE_GLOB;
    int n = b2 & 255, half = b2 >> 8;
    if (half == 0) {
      __shared__ float wred[8];
      int tid = threadIdx.x, lane = tid & 63, wv = tid >> 6;
      float sgv = 0.0f, sbv = 0.0f;
      #pragma unroll
      for (int kk = 0; kk < 2; ++kk) {
        int k = tid + kk * 256;
        float w = Win[(size_t)k * HID + n];
        float wg = w * g_in[k];
        _Float16 h = (_Float16)wg;
        size_t pi = pack_idx(k, n);
        Pgh[pi] = h;
        Pgl[pi] = (_Float16)(wg - (float)h);
        sgv += wg;
        sbv = fmaf(b_in[k], w, sbv);
      }
      #pragma unroll
      for (int m = 1; m < 64; m <<= 1) { sgv += __shfl_xor(sgv, m); sbv += __shfl_xor(sbv, m); }
      if (lane == 0) { wred[wv * 2] = sgv; wred[wv * 2 + 1] = sbv; }
      __syncthreads();
      if (tid == 0) {
        gwv[n] = wred[0] + wred[2] + wred[4] + wred[6];
        bwv[n] = wred[1] + wred[3] + wred[5] + wred[7];
      }
    } else {
      int k = threadIdx.x;
      float v = Wout1[(size_t)k * HID + n];
      _Float16 h = (_Float16)v;
      size_t pi = pack_idx(k, n);
      P1h[pi] = h;
      P1l[pi] = (_Float16)(v - (float)h);
    }
  } else {
    int r = (bid - PRE_GLOB - PRE_PREP) * 4 + (threadIdx.x >> 6);
    int lane = threadIdx.x & 63;
    const float4* xr = (const float4*)(x + (size_t)r * DIM);
    float4 a = xr[lane], c = xr[lane + 64];
    double s = (double)a.x + a.y + a.z + a.w + (double)c.x + c.y + c.z + c.w;
    double q = (double)a.x * a.x + (double)a.y * a.y + (double)a.z * a.z + (double)a.w * a.w +
               (double)c.x * c.x + (double)c.y * c.y + (double)c.z * c.z + (double)c.w * c.w;
    #pragma unroll
    for (int m = 1; m < 64; m <<= 1) { s += __shfl_xor(s, m); q += __shfl_xor(q, m); }
    if (lane == 0) {
      double mean = s / 512.0;
      double var = q / 512.0 - mean * mean;
      stats[r * 2]     = (float)mean;
      stats[r * 2 + 1] = (float)(1.0 / sqrt(var + 1e-5));
    }
  }
}

// ---------- shared GEMM machinery: all-register, no barriers in K-loop ----------
#define LOADA(src0, src1, t, pb)                                               \
  {                                                                            \
    axv[pb][0] = *(const float4*)((src0) + (t) * 32);                          \
    axv[pb][1] = *(const float4*)((src0) + (t) * 32 + 4);                      \
    axv[pb][2] = *(const float4*)((src1) + (t) * 32);                          \
    axv[pb][3] = *(const float4*)((src1) + (t) * 32 + 4);                      \
  }

#define LOADA_LDS(t, pb)                                                       \
  {                                                                            \
    axv[pb][0] = *(const float4*)&stage[lr * SPAD + (t) * 32 + kg * 8];        \
    axv[pb][1] = *(const float4*)&stage[lr * SPAD + (t) * 32 + kg * 8 + 4];    \
    axv[pb][2] = *(const float4*)&stage[(16 + lr) * SPAD + (t) * 32 + kg * 8]; \
    axv[pb][3] = *(const float4*)&stage[(16 + lr) * SPAD + (t) * 32 + kg * 8 + 4]; \
  }

#define LOADB(bh, bl, t, pb)                                                   \
  {                                                                            \
    _Pragma("unroll")                                                          \
    for (int ni = 0; ni < 4; ++ni) {                                           \
      bxh[pb][ni] = *(const f16x8*)((bh) + (size_t)(t) * 8192 + ni * 128);     \
      bxl[pb][ni] = *(const f16x8*)((bl) + (size_t)(t) * 8192 + ni * 128);     \
    }                                                                          \
  }

#define SPLITA(pb, fah, fal)                                                   \
  {                                                                            \
    _Pragma("unroll")                                                          \
    for (int mi = 0; mi < 2; ++mi) {                                           \
      float va[8];                                                             \
      *(float4*)&va[0] = axv[pb][mi * 2];                                      \
      *(float4*)&va[4] = axv[pb][mi * 2 + 1];                                  \
      _Pragma("unroll")                                                        \
      for (int e = 0; e < 8; ++e) {                                            \
        _Float16 h = (_Float16)va[e];                                          \
        fah[mi][e] = h;                                                        \
        fal[mi][e] = (_Float16)(va[e] - (float)h);                             \
      }                                                                        \
    }                                                                          \
  }

#define MFMA_CHUNK(pb, fah, fal)                                               \
  {                                                                            \
    _Pragma("unroll")                                                          \
    for (int mi = 0; mi < 2; ++mi)                                             \
      _Pragma("unroll")                                                        \
      for (int ni = 0; ni < 4; ++ni) {                                         \
        acc[mi][ni] = __builtin_amdgcn_mfma_f32_16x16x32_f16(fah[mi], bxh[pb][ni], acc[mi][ni], 0, 0, 0); \
        acc[mi][ni] = __builtin_amdgcn_mfma_f32_16x16x32_f16(fah[mi], bxl[pb][ni], acc[mi][ni], 0, 0, 0); \
        acc[mi][ni] = __builtin_amdgcn_mfma_f32_16x16x32_f16(fal[mi], bxh[pb][ni], acc[mi][ni], 0, 0, 0); \
      }                                                                        \
  }

// ---------- K1: fused GEMM1 -> (LDS) -> GEMM2 -> scores ----------
// 32 rows/block. Phase B: local = gelu(LN-folded x@Wg) into LDS stage.
// Phase C: U = stage @ W1 (A from LDS, B fragment-major global), epilogue -> scores.
__global__ __launch_bounds__(256) void k_gemm(
    const float* __restrict__ x, const float* __restrict__ stats,
    const _Float16* __restrict__ Pgh, const _Float16* __restrict__ Pgl,
    const float* __restrict__ gwv, const float* __restrict__ bwv,
    const _Float16* __restrict__ P1h, const _Float16* __restrict__ P1l,
    const float* __restrict__ W2, const float* __restrict__ c1,
    const float* __restrict__ c2, float* __restrict__ scores) {
  __shared__ float stage[32 * SPAD];   // 33.3 KB
  __shared__ float red1[32][4], red2[32][4];
  const int tid = threadIdx.x, lane = tid & 63, w = tid >> 6;
  const int kg = lane >> 4, lr = lane & 15;
  const int gr0 = blockIdx.x * 32;

  const float* asrc0 = x + (size_t)(gr0 + lr) * DIM + kg * 8;
  const float* asrc1 = x + (size_t)(gr0 + 16 + lr) * DIM + kg * 8;
  const _Float16* bh = Pgh + ((size_t)kg * 256 + w * 64 + lr) * 8;
  const _Float16* bl = Pgl + ((size_t)kg * 256 + w * 64 + lr) * 8;
  const _Float16* bh2 = P1h + ((size_t)kg * 256 + w * 64 + lr) * 8;
  const _Float16* bl2 = P1l + ((size_t)kg * 256 + w * 64 + lr) * 8;

  f32x4 acc[2][4];
  const f32x4 z4 = {0.f, 0.f, 0.f, 0.f};
  #pragma unroll
  for (int mi = 0; mi < 2; ++mi)
    #pragma unroll
    for (int ni = 0; ni < 4; ++ni) acc[mi][ni] = z4;
  float4 axv[2][4];
  f16x8 bxh[2][4], bxl[2][4];

  // ---- phase B: acc = x @ Wg ----
  LOADA(asrc0, asrc1, 0, 0)
  LOADB(bh, bl, 0, 0)
  #pragma unroll
  for (int t = 0; t < 16; ++t) {
    const int pb = t & 1;
    if (t + 1 < 16) {
      LOADA(asrc0, asrc1, t + 1, pb ^ 1)
      LOADB(bh, bl, t + 1, pb ^ 1)
    }
    f16x8 fah[2], fal[2];
    SPLITA(pb, fah, fal)
    MFMA_CHUNK(pb, fah, fal)
  }

  // ---- LN fold + gelu -> LDS stage ----
  {
    float gwc[4], bwc[4];
    #pragma unroll
    for (int ni = 0; ni < 4; ++ni) {
      int col = w * 64 + ni * 16 + lr;
      gwc[ni] = gwv[col];
      bwc[ni] = bwv[col];
    }
    #pragma unroll
    for (int mi = 0; mi < 2; ++mi)
      #pragma unroll
      for (int i = 0; i < 4; ++i) {
        int rrel = mi * 16 + kg * 4 + i;
        int row = gr0 + rrel;
        float mn = stats[row * 2], rs = stats[row * 2 + 1];
        #pragma unroll
        for (int ni = 0; ni < 4; ++ni) {
          int col = w * 64 + ni * 16 + lr;
          float v = rs * acc[mi][ni][i] - rs * mn * gwc[ni] + bwc[ni];
          stage[rrel * SPAD + col] = gelu32(v);
        }
      }
  }
  LOADB(bh2, bl2, 0, 0)          // prefetch first W1 tile before the barrier
  __syncthreads();

  // ---- phase C: acc = stage @ W1 ----
  #pragma unroll
  for (int mi = 0; mi < 2; ++mi)
    #pragma unroll
    for (int ni = 0; ni < 4; ++ni) acc[mi][ni] = z4;
  LOADA_LDS(0, 0)
  #pragma unroll
  for (int t = 0; t < 8; ++t) {
    const int pb = t & 1;
    if (t + 1 < 8) {
      LOADA_LDS(t + 1, pb ^ 1)
      LOADB(bh2, bl2, t + 1, pb ^ 1)
    }
    f16x8 fah[2], fal[2];
    SPLITA(pb, fah, fal)
    MFMA_CHUNK(pb, fah, fal)
  }

  // ---- epilogue -> scores ----
  float w2v[4];
  #pragma unroll
  for (int ni = 0; ni < 4; ++ni) w2v[ni] = W2[w * 64 + ni * 16 + lr];
  #pragma unroll
  for (int mi = 0; mi < 2; ++mi) {
    #pragma unroll
    for (int i = 0; i < 4; ++i) {
      int row = gr0 + mi * 16 + kg * 4 + i;
      int bf = row / NTOK;
      float p1 = 0.f, p2 = 0.f;
      #pragma unroll
      for (int ni = 0; ni < 4; ++ni) {
        int col = w * 64 + ni * 16 + lr;
        float u = acc[mi][ni][i];
        p1 = fmaf(gelu32(u + c1[(size_t)bf * HID + col]), w2v[ni], p1);
        p2 = fmaf(gelu32(u + c2[(size_t)bf * HID + col]), w2v[ni], p2);
      }
      #pragma unroll
      for (int m = 1; m < 16; m <<= 1) { p1 += __shfl_xor(p1, m); p2 += __shfl_xor(p2, m); }
      if (lr == 0) {
        red1[mi * 16 + kg * 4 + i][w] = p1;
        red2[mi * 16 + kg * 4 + i][w] = p2;
      }
    }
  }
  __syncthreads();
  if (tid < 32) {
    float s1 = red1[tid][0] + red1[tid][1] + red1[tid][2] + red1[tid][3];
    float s2 = red2[tid][0] + red2[tid][1] + red2[tid][2] + red2[tid][3];
    scores[gr0 + tid] = tanhf(s1) + tanhf(s2);
  }
}

// ---------- K2: perturbed top-k, tail-batched RNG, early-exit search ----------
__global__ __launch_bounds__(512) void k_topk(const float* __restrict__ scores,
                                              unsigned short* __restrict__ partial) {
  const int b = blockIdx.x, chunk = blockIdx.y;
  const int tid = threadIdx.x, lane = tid & 63, wv = tid >> 6;
  __shared__ float sc_s[NTOK];
  __shared__ int cnt_s[CNTSZ];
  if (tid < NTOK) sc_s[tid] = scores[b * NTOK + tid];
  for (int i = tid; i < CNTSZ; i += 512) cnt_s[i] = 0;

  const int s_first = chunk + SPB * wv;
  const unsigned gb = (unsigned)b * NS * 196u;

  float n_tail = 0.0f;
  {
    int si = lane >> 2, t = lane & 3;
    int s = s_first + si * (SPB * 8);
    if (lane < 28 && s < NS) {
      n_tail = noise_at(gb + (unsigned)s * 196u + 192u + (unsigned)t);
    }
  }
  __syncthreads();

  int si = 0;
  for (int s = s_first; s < NS; s += SPB * 8, ++si) {
    const unsigned gbase = gb + (unsigned)s * 196u;
    unsigned key[4];
    #pragma unroll
    for (int c = 0; c < 3; ++c) {
      float n = noise_at(gbase + (unsigned)(c * 64 + lane));
      float p = fmaf(0.05f, n, sc_s[c * 64 + lane]);
      unsigned ub = __float_as_uint(p);
      key[c] = (ub & 0x80000000u) ? ~ub : (ub | 0x80000000u);
    }
    {
      float n = __shfl(n_tail, si * 4 + (lane & 3));
      float p = fmaf(0.05f, n, sc_s[192 + (lane & 3)]);
      unsigned ub = __float_as_uint(p);
      unsigned k3 = (ub & 0x80000000u) ? ~ub : (ub | 0x80000000u);
      key[3] = (lane < 4) ? k3 : 0u;
    }
    unsigned prefix = 0u;
    bool exact = false;
    for (int bit = 31; bit >= 0; --bit) {
      unsigned t = prefix | (1u << bit);
      int cn = 0;
      #pragma unroll
      for (int c = 0; c < 4; ++c) cn += __popcll(__ballot(key[c] >= t));
      if (cn >= TOPK) {
        prefix = t;
        if (cn == TOPK) { exact = true; break; }
      }
    }
    unsigned long long lt = (1ull << lane) - 1ull;
    bool sel[4];
    if (exact) {
      #pragma unroll
      for (int c = 0; c < 4; ++c) sel[c] = key[c] >= prefix;
    } else {
      unsigned long long mE[4];
      int cntG = 0;
      #pragma unroll
      for (int c = 0; c < 4; ++c) {
        cntG += __popcll(__ballot(key[c] > prefix));
        mE[c] = __ballot(key[c] == prefix);
      }
      int need = TOPK - cntG;
      #pragma unroll
      for (int c = 0; c < 4; ++c) {
        int er = 0;
        for (int cc = 0; cc < c; ++cc) er += __popcll(mE[cc]);
        er += __popcll(mE[c] & lt);
        sel[c] = (key[c] > prefix) || ((key[c] == prefix) && (er < need));
      }
    }
    unsigned long long mS[4];
    #pragma unroll
    for (int c = 0; c < 4; ++c) mS[c] = __ballot(sel[c]);
    int base = 0;
    #pragma unroll
    for (int c = 0; c < 4; ++c) {
      if (sel[c]) {
        int rank = base + __popcll(mS[c] & lt);
        int j = c * 64 + lane;
        atomicAdd(&cnt_s[rank * NTOK + j], 1);
      }
      base += __popcll(mS[c]);
    }
  }
  __syncthreads();
  unsigned short* dst = partial + ((size_t)b * SPB + chunk) * CNTSZ;
  for (int i = tid; i < CNTSZ; i += 512) dst[i] = (unsigned short)cnt_s[i];
}

// ---------- K3: out[b,k,:] = sum_l (sum_c partial)/500 * x[b,l,:] ----------
// grid transposed: bid = k*BP + b -> all 49 blocks of frame b share bid%8
// (same XCD L2) so x[b]'s 400KB slice is fetched from HBM once, not 8x.
__global__ __launch_bounds__(256) void k_out(const float* __restrict__ x,
                                             const unsigned short* __restrict__ partial,
                                             float* __restrict__ out) {
  int bid = blockIdx.x;
  int b = bid % BP, k = bid / BP;
  __shared__ float swv[NTOK];
  __shared__ int idxs[NTOK];
  __shared__ int wcnt[4];
  __shared__ int wbase[5];
  __shared__ float4 part2[128];
  const int tid = threadIdx.x, lane = tid & 63, wv = tid >> 6;

  int cval = 0;
  if (tid < NTOK) {
    #pragma unroll
    for (int cc = 0; cc < SPB; ++cc)
      cval += partial[((size_t)b * SPB + cc) * CNTSZ + k * NTOK + tid];
  }
  unsigned long long m = __ballot(cval != 0);
  if (lane == 0) wcnt[wv] = __popcll(m);
  __syncthreads();
  if (tid == 0) {
    int a = 0;
    #pragma unroll
    for (int i = 0; i < 4; ++i) { wbase[i] = a; a += wcnt[i]; }
    wbase[4] = a;
  }
  __syncthreads();
  if (cval != 0) {
    int pos = wbase[wv] + __popcll(m & ((1ull << lane) - 1ull));
    idxs[pos] = tid;
    swv[pos] = (float)cval * 0.002f;
  }
  __syncthreads();
  const int n = wbase[4];
  const int half = tid >> 7, d4 = tid & 127;
  const int i0 = half ? (n + 1) / 2 : 0;
  const int i1 = half ? n : (n + 1) / 2;
  float a0 = 0, a1 = 0, a2 = 0, a3 = 0;
  for (int i = i0; i < i1; ++i) {
    float w = swv[i];
    float4 xv = *(const float4*)(x + ((size_t)(b * NTOK + idxs[i])) * DIM + d4 * 4);
    a0 = fmaf(w, xv.x, a0); a1 = fmaf(w, xv.y, a1);
    a2 = fmaf(w, xv.z, a2); a3 = fmaf(w, xv.w, a3);
  }
  if (half == 1) part2[d4] = make_float4(a0, a1, a2, a3);
  __syncthreads();
  if (half == 0) {
    float4 p = part2[d4];
    float4 o = make_float4(a0 + p.x, a1 + p.y, a2 + p.z, a3 + p.w);
    *(float4*)(out + ((size_t)(b * TOPK + k)) * DIM + d4 * 4) = o;
  }
}

// ---------- launcher ----------
extern "C" void kernel_launch(void* const* d_in, const int* in_sizes, int n_in,
                              void* d_out, int out_size, void* d_ws, size_t ws_size,
                              hipStream_t stream) {
  const float* x       = (const float*)d_in[0];
  const float* gf      = (const float*)d_in[1];
  const float* gs      = (const float*)d_in[2];
  const float* ln_in_g = (const float*)d_in[3];
  const float* ln_in_b = (const float*)d_in[4];
  const float* W_in    = (const float*)d_in[5];
  const float* ln_gd_g = (const float*)d_in[6];
  const float* ln_gd_b = (const float*)d_in[7];
  const float* W_gd    = (const float*)d_in[8];
  const float* W_out1  = (const float*)d_in[9];
  const float* W_out2  = (const float*)d_in[10];
  float* out = (float*)d_out;

  // ws layout (~21 MB; local_ round-trip eliminated)
  char* p = (char*)d_ws;
  unsigned short* partial = (unsigned short*)p; p += (size_t)BP * SPB * CNTSZ * 2; // 18.4 MB
  float* stats   = (float*)p;             p += (size_t)ROWS * 2 * 4;
  float* c1      = (float*)p;             p += (size_t)BP * HID * 4;
  float* c2      = (float*)p;             p += (size_t)BP * HID * 4;
  float* scores  = (float*)p;             p += (size_t)ROWS * 4;
  _Float16* Pgh  = (_Float16*)p;          p += (size_t)HID * DIM * 2;
  _Float16* Pgl  = (_Float16*)p;          p += (size_t)HID * DIM * 2;
  _Float16* P1h  = (_Float16*)p;          p += (size_t)HID * HID * 2;
  _Float16* P1l  = (_Float16*)p;          p += (size_t)HID * HID * 2;
  float* gwv     = (float*)p;             p += HID * 4;
  float* bwv     = (float*)p;             p += HID * 4;

  k_pre<<<PRE_GLOB + PRE_PREP + PRE_STATS, 256, 0, stream>>>(
      gf, gs, ln_gd_g, ln_gd_b, W_gd, W_out1, c1,
      W_in, ln_in_g, ln_in_b, Pgh, Pgl, P1h, P1l, gwv, bwv, x, stats);
  k_gemm<<<GBLK, 256, 0, stream>>>(x, stats, Pgh, Pgl, gwv, bwv,
                                   P1h, P1l, W_out2, c1, c2, scores);
  k_topk<<<dim3(BP, SPB), 512, 0, stream>>>(scores, partial);
  k_out<<<BP * TOPK, 256, 0, stream>>>(x, partial, out);
}

// Round 20
// 150.186 us; speedup vs baseline: 2.0107x; 1.0309x over previous
//
#include <hip/hip_runtime.h>
#include <stdint.h>

#define DEV __device__ __forceinline__

// ---------- problem constants ----------
#define BP 96
#define NTOK 196
#define DIM 512
#define HID 256
#define NS 500
#define TOPK 49
#define ROWS (BP * NTOK)          // 18816
#define GBLK (ROWS / 32)          // 588 blocks for the fused MFMA GEMM
#define SPB 10                    // sample-chunks per frame-batch
#define CNTSZ (TOPK * NTOK)       // 9604
#define SPAD 260                  // stage row stride (floats)

typedef _Float16 f16x8 __attribute__((ext_vector_type(8)));
typedef float f32x4 __attribute__((ext_vector_type(4)));

// ---------- math helpers ----------
DEV float gelu32(float v) {
  return 0.5f * v * (1.0f + erff(v * 0.70710678f));
}

// Threefry-2x32, 20 rounds, key = (0, 1)  (jax.random.key(1))
DEV void threefry2x32(uint32_t x0, uint32_t x1, uint32_t& o0, uint32_t& o1) {
  const uint32_t k0 = 0u, k1 = 1u;
  const uint32_t k2 = 0x1BD11BDAu ^ k0 ^ k1;
  x0 += k0; x1 += k1;
#define TF_R(r) { x0 += x1; x1 = (x1 << (r)) | (x1 >> (32 - (r))); x1 ^= x0; }
  TF_R(13) TF_R(15) TF_R(26) TF_R(6)
  x0 += k1; x1 += k2 + 1u;
  TF_R(17) TF_R(29) TF_R(16) TF_R(24)
  x0 += k2; x1 += k0 + 2u;
  TF_R(13) TF_R(15) TF_R(26) TF_R(6)
  x0 += k0; x1 += k1 + 3u;
  TF_R(17) TF_R(29) TF_R(16) TF_R(24)
  x0 += k1; x1 += k2 + 4u;
  TF_R(13) TF_R(15) TF_R(26) TF_R(6)
  x0 += k2; x1 += k0 + 5u;
#undef TF_R
  o0 = x0; o1 = x1;
}

// XLA ErfInv32 (Giles polynomial). w via native v_log_f32 (flip-safe, r13-proven)
DEV float erfinv_xla(float x) {
  float w = -__logf(fmaf(-x, x, 1.0f));
  float ws = w - 2.5f;
  float ps = 2.81022636e-08f;
  ps = fmaf(ps, ws, 3.43273939e-07f);
  ps = fmaf(ps, ws, -3.5233877e-06f);
  ps = fmaf(ps, ws, -4.39150654e-06f);
  ps = fmaf(ps, ws, 0.00021858087f);
  ps = fmaf(ps, ws, -0.00125372503f);
  ps = fmaf(ps, ws, -0.00417768164f);
  ps = fmaf(ps, ws, 0.246640727f);
  ps = fmaf(ps, ws, 1.50140941f);
  float r = ps;
  if (__ballot(w >= 5.0f) != 0ull) {
    float wl = sqrtf(w) - 3.0f;
    float pl = -0.000200214257f;
    pl = fmaf(pl, wl, 0.000100950558f);
    pl = fmaf(pl, wl, 0.00134934322f);
    pl = fmaf(pl, wl, -0.00367342844f);
    pl = fmaf(pl, wl, 0.00573950773f);
    pl = fmaf(pl, wl, -0.0076224613f);
    pl = fmaf(pl, wl, 0.00943887047f);
    pl = fmaf(pl, wl, 1.00167406f);
    pl = fmaf(pl, wl, 2.83297682f);
    r = (w < 5.0f) ? ps : pl;
  }
  return r * x;
}

// jax-f32-faithful N(0,1) noise, PARTITIONABLE threefry: counter=(0,g), draw=o0^o1
DEV float noise_at(unsigned g) {
  unsigned o0, o1;
  threefry2x32(0u, g, o0, o1);
  unsigned bits = o0 ^ o1;
  float f = __uint_as_float((bits >> 9) | 0x3f800000u) - 1.0f;
  float u = f * 2.0f - 0.99999994f;
  u = fmaxf(-0.99999994f, u);
  return 1.41421356f * erfinv_xla(u);
}

// fragment-major weight packing: P[((t*4+kg)*256 + col)*8 + e] = W[k=t*32+kg*8+e][col]
DEV size_t pack_idx(int k, int col) {
  int t = k >> 5, kg = (k >> 3) & 3, e = k & 7;
  return (((size_t)(t * 4 + kg) * 256) + col) * 8 + e;
}

// ---------- K0: merged pre-pass: glob | wprep | stats | x-pack ----------
#define PRE_GLOB 192
#define PRE_PREP 512
#define PRE_STATS (ROWS / 4)
#define PRE_PACK (GBLK * 8)
__global__ __launch_bounds__(256) void k_pre(
    const float* __restrict__ gf, const float* __restrict__ gs,
    const float* __restrict__ lng, const float* __restrict__ lnb,
    const float* __restrict__ Wgd, const float* __restrict__ Wout1,
    float* __restrict__ cout,
    const float* __restrict__ Win,
    const float* __restrict__ g_in, const float* __restrict__ b_in,
    _Float16* __restrict__ Pgh, _Float16* __restrict__ Pgl,
    _Float16* __restrict__ P1h, _Float16* __restrict__ P1l,
    float* __restrict__ gwv, float* __restrict__ bwv,
    const float* __restrict__ x, float* __restrict__ stats,
    _Float16* __restrict__ xPh, _Float16* __restrict__ xPl) {
  const int bid = blockIdx.x;
  if (bid < PRE_GLOB) {
    int bq = bid >> 1, which = bid & 1;
    const float* row = which ? (gs + (size_t)(bq / 12) * DIM) : (gf + (size_t)bq * DIM);
    __shared__ float lx[DIM];
    __shared__ float sg[HID];
    __shared__ double sred[8];
    int tid = threadIdx.x, lane = tid & 63, wv = tid >> 6;
    float v0 = row[tid], v1 = row[tid + 256];
    double s = (double)v0 + v1, q = (double)v0 * v0 + (double)v1 * v1;
    #pragma unroll
    for (int m = 1; m < 64; m <<= 1) { s += __shfl_xor(s, m); q += __shfl_xor(q, m); }
    if (lane == 0) { sred[wv * 2] = s; sred[wv * 2 + 1] = q; }
    __syncthreads();
    double ts = sred[0] + sred[2] + sred[4] + sred[6];
    double tq = sred[1] + sred[3] + sred[5] + sred[7];
    double mean = ts / 512.0;
    double var = tq / 512.0 - mean * mean;
    float mn = (float)mean;
    float rs = (float)(1.0 / sqrt(var + 1e-5));
    lx[tid]       = (v0 - mn) * rs * lng[tid] + lnb[tid];
    lx[tid + 256] = (v1 - mn) * rs * lng[tid + 256] + lnb[tid + 256];
    __syncthreads();
    float acc = 0.0f;
    for (int d = 0; d < DIM; ++d) acc = fmaf(lx[d], Wgd[(size_t)d * HID + tid], acc);
    sg[tid] = gelu32(acc);
    __syncthreads();
    float c = 0.0f;
    for (int j = 0; j < HID; ++j) c = fmaf(sg[j], Wout1[(size_t)(HID + j) * HID + tid], c);
    cout[((size_t)which * BP + bq) * HID + tid] = c;
  } else if (bid < PRE_GLOB + PRE_PREP) {
    int b2 = bid - PRE_GLOB;
    int n = b2 & 255, half = b2 >> 8;
    if (half == 0) {
      __shared__ float wred[8];
      int tid = threadIdx.x, lane = tid & 63, wv = tid >> 6;
      float sgv = 0.0f, sbv = 0.0f;
      #pragma unroll
      for (int kk = 0; kk < 2; ++kk) {
        int k = tid + kk * 256;
        float w = Win[(size_t)k * HID + n];
        float wg = w * g_in[k];
        _Float16 h = (_Float16)wg;
        size_t pi = pack_idx(k, n);
        Pgh[pi] = h;
        Pgl[pi] = (_Float16)(wg - (float)h);
        sgv += wg;
        sbv = fmaf(b_in[k], w, sbv);
      }
      #pragma unroll
      for (int m = 1; m < 64; m <<= 1) { sgv += __shfl_xor(sgv, m); sbv += __shfl_xor(sbv, m); }
      if (lane == 0) { wred[wv * 2] = sgv; wred[wv * 2 + 1] = sbv; }
      __syncthreads();
      if (tid == 0) {
        gwv[n] = wred[0] + wred[2] + wred[4] + wred[6];
        bwv[n] = wred[1] + wred[3] + wred[5] + wred[7];
      }
    } else {
      int k = threadIdx.x;
      float v = Wout1[(size_t)k * HID + n];
      _Float16 h = (_Float16)v;
      size_t pi = pack_idx(k, n);
      P1h[pi] = h;
      P1l[pi] = (_Float16)(v - (float)h);
    }
  } else if (bid < PRE_GLOB + PRE_PREP + PRE_STATS) {
    int r = (bid - PRE_GLOB - PRE_PREP) * 4 + (threadIdx.x >> 6);
    int lane = threadIdx.x & 63;
    const float4* xr = (const float4*)(x + (size_t)r * DIM);
    float4 a = xr[lane], c = xr[lane + 64];
    double s = (double)a.x + a.y + a.z + a.w + (double)c.x + c.y + c.z + c.w;
    double q = (double)a.x * a.x + (double)a.y * a.y + (double)a.z * a.z + (double)a.w * a.w +
               (double)c.x * c.x + (double)c.y * c.y + (double)c.z * c.z + (double)c.w * c.w;
    #pragma unroll
    for (int m = 1; m < 64; m <<= 1) { s += __shfl_xor(s, m); q += __shfl_xor(q, m); }
    if (lane == 0) {
      double mean = s / 512.0;
      double var = q / 512.0 - mean * mean;
      stats[r * 2]     = (float)mean;
      stats[r * 2 + 1] = (float)(1.0 / sqrt(var + 1e-5));
    }
  } else {
    // ---- x-pack: 32-row panel rb, 64-col chunk cc -> fragment-major split fp16 ----
    int idx = bid - PRE_GLOB - PRE_PREP - PRE_STATS;
    int rb = idx >> 3, cc = idx & 7;
    __shared__ float cbuf[32][67];
    const int tid = threadIdx.x;
    {
      int r = tid >> 3, c8 = (tid & 7) * 8;
      const float* src = x + ((size_t)rb * 32 + r) * DIM + cc * 64 + c8;
      float4 v0 = *(const float4*)src;
      float4 v1 = *(const float4*)(src + 4);
      *(float4*)&cbuf[r][c8] = v0;
      *(float4*)&cbuf[r][c8 + 4] = v1;
    }
    __syncthreads();
    {
      int combo = tid >> 5;          // 0..7: tloc = combo>>2, kg = combo&3
      int tloc = combo >> 2, kg = combo & 3;
      int r = tid & 31;
      int t = cc * 2 + tloc;
      f16x8 h8, l8;
      #pragma unroll
      for (int e = 0; e < 8; ++e) {
        float v = cbuf[r][tloc * 32 + kg * 8 + e];
        _Float16 h = (_Float16)v;
        h8[e] = h;
        l8[e] = (_Float16)(v - (float)h);
      }
      size_t off = (size_t)rb * 16384 + (((size_t)t * 4 + kg) * 32 + r) * 8;
      *(f16x8*)(xPh + off) = h8;
      *(f16x8*)(xPl + off) = l8;
    }
  }
}

// ---------- shared GEMM machinery ----------
#define LOADAF(axh, axl, t, pb)                                                \
  {                                                                            \
    fahb[pb][0] = *(const f16x8*)((axh) + (t) * 1024);                         \
    fahb[pb][1] = *(const f16x8*)((axh) + (t) * 1024 + 128);                   \
    falb[pb][0] = *(const f16x8*)((axl) + (t) * 1024);                         \
    falb[pb][1] = *(const f16x8*)((axl) + (t) * 1024 + 128);                   \
  }

#define LOADA_LDS(t, pb)                                                       \
  {                                                                            \
    axv[pb][0] = *(const float4*)&stage[lr * SPAD + (t) * 32 + kg * 8];        \
    axv[pb][1] = *(const float4*)&stage[lr * SPAD + (t) * 32 + kg * 8 + 4];    \
    axv[pb][2] = *(const float4*)&stage[(16 + lr) * SPAD + (t) * 32 + kg * 8]; \
    axv[pb][3] = *(const float4*)&stage[(16 + lr) * SPAD + (t) * 32 + kg * 8 + 4]; \
  }

#define LOADB(bh, bl, t, pb)                                                   \
  {                                                                            \
    _Pragma("unroll")                                                          \
    for (int ni = 0; ni < 4; ++ni) {                                           \
      bxh[pb][ni] = *(const f16x8*)((bh) + (size_t)(t) * 8192 + ni * 128);     \
      bxl[pb][ni] = *(const f16x8*)((bl) + (size_t)(t) * 8192 + ni * 128);     \
    }                                                                          \
  }

#define SPLITA(pb, fah, fal)                                                   \
  {                                                                            \
    _Pragma("unroll")                                                          \
    for (int mi = 0; mi < 2; ++mi) {                                           \
      float va[8];                                                             \
      *(float4*)&va[0] = axv[pb][mi * 2];                                      \
      *(float4*)&va[4] = axv[pb][mi * 2 + 1];                                  \
      _Pragma("unroll")                                                        \
      for (int e = 0; e < 8; ++e) {                                            \
        _Float16 h = (_Float16)va[e];                                          \
        fah[mi][e] = h;                                                        \
        fal[mi][e] = (_Float16)(va[e] - (float)h);                             \
      }                                                                        \
    }                                                                          \
  }

#define MFMA_CHUNK(fah, fal)                                                   \
  {                                                                            \
    _Pragma("unroll")                                                          \
    for (int mi = 0; mi < 2; ++mi)                                             \
      _Pragma("unroll")                                                        \
      for (int ni = 0; ni < 4; ++ni) {                                         \
        acc[mi][ni] = __builtin_amdgcn_mfma_f32_16x16x32_f16(fah[mi], bxh[pb][ni], acc[mi][ni], 0, 0, 0); \
        acc[mi][ni] = __builtin_amdgcn_mfma_f32_16x16x32_f16(fah[mi], bxl[pb][ni], acc[mi][ni], 0, 0, 0); \
        acc[mi][ni] = __builtin_amdgcn_mfma_f32_16x16x32_f16(fal[mi], bxh[pb][ni], acc[mi][ni], 0, 0, 0); \
      }                                                                        \
  }

// ---------- K1: fused GEMM1 -> (LDS) -> GEMM2 -> scores ----------
__global__ __launch_bounds__(256) void k_gemm(
    const _Float16* __restrict__ xPh, const _Float16* __restrict__ xPl,
    const float* __restrict__ stats,
    const _Float16* __restrict__ Pgh, const _Float16* __restrict__ Pgl,
    const float* __restrict__ gwv, const float* __restrict__ bwv,
    const _Float16* __restrict__ P1h, const _Float16* __restrict__ P1l,
    const float* __restrict__ W2, const float* __restrict__ c1,
    const float* __restrict__ c2, float* __restrict__ scores) {
  __shared__ float stage[32 * SPAD];   // 33.3 KB
  __shared__ float red1[32][4], red2[32][4];
  const int tid = threadIdx.x, lane = tid & 63, w = tid >> 6;
  const int kg = lane >> 4, lr = lane & 15;
  const int gr0 = blockIdx.x * 32;

  const _Float16* axh = xPh + (size_t)blockIdx.x * 16384 + ((size_t)kg * 32 + lr) * 8;
  const _Float16* axl = xPl + (size_t)blockIdx.x * 16384 + ((size_t)kg * 32 + lr) * 8;
  const _Float16* bh = Pgh + ((size_t)kg * 256 + w * 64 + lr) * 8;
  const _Float16* bl = Pgl + ((size_t)kg * 256 + w * 64 + lr) * 8;
  const _Float16* bh2 = P1h + ((size_t)kg * 256 + w * 64 + lr) * 8;
  const _Float16* bl2 = P1l + ((size_t)kg * 256 + w * 64 + lr) * 8;

  f32x4 acc[2][4];
  const f32x4 z4 = {0.f, 0.f, 0.f, 0.f};
  #pragma unroll
  for (int mi = 0; mi < 2; ++mi)
    #pragma unroll
    for (int ni = 0; ni < 4; ++ni) acc[mi][ni] = z4;
  f16x8 fahb[2][2], falb[2][2];
  f16x8 bxh[2][4], bxl[2][4];

  // ---- phase B: acc = x @ Wg  (A fragment-major, no split needed) ----
  LOADAF(axh, axl, 0, 0)
  LOADB(bh, bl, 0, 0)
  #pragma unroll
  for (int t = 0; t < 16; ++t) {
    const int pb = t & 1;
    if (t + 1 < 16) {
      LOADAF(axh, axl, t + 1, pb ^ 1)
      LOADB(bh, bl, t + 1, pb ^ 1)
    }
    MFMA_CHUNK(fahb[pb], falb[pb])
  }

  // ---- LN fold + gelu -> LDS stage ----
  {
    float gwc[4], bwc[4];
    #pragma unroll
    for (int ni = 0; ni < 4; ++ni) {
      int col = w * 64 + ni * 16 + lr;
      gwc[ni] = gwv[col];
      bwc[ni] = bwv[col];
    }
    #pragma unroll
    for (int mi = 0; mi < 2; ++mi)
      #pragma unroll
      for (int i = 0; i < 4; ++i) {
        int rrel = mi * 16 + kg * 4 + i;
        int row = gr0 + rrel;
        float mn = stats[row * 2], rs = stats[row * 2 + 1];
        #pragma unroll
        for (int ni = 0; ni < 4; ++ni) {
          int col = w * 64 + ni * 16 + lr;
          float v = rs * acc[mi][ni][i] - rs * mn * gwc[ni] + bwc[ni];
          stage[rrel * SPAD + col] = gelu32(v);
        }
      }
  }
  LOADB(bh2, bl2, 0, 0)          // prefetch first W1 tile before the barrier
  __syncthreads();

  // ---- phase C: acc = stage @ W1 ----
  #pragma unroll
  for (int mi = 0; mi < 2; ++mi)
    #pragma unroll
    for (int ni = 0; ni < 4; ++ni) acc[mi][ni] = z4;
  float4 axv[2][4];
  LOADA_LDS(0, 0)
  #pragma unroll
  for (int t = 0; t < 8; ++t) {
    const int pb = t & 1;
    if (t + 1 < 8) {
      LOADA_LDS(t + 1, pb ^ 1)
      LOADB(bh2, bl2, t + 1, pb ^ 1)
    }
    f16x8 fah[2], fal[2];
    SPLITA(pb, fah, fal)
    MFMA_CHUNK(fah, fal)
  }

  // ---- epilogue -> scores ----
  float w2v[4];
  #pragma unroll
  for (int ni = 0; ni < 4; ++ni) w2v[ni] = W2[w * 64 + ni * 16 + lr];
  #pragma unroll
  for (int mi = 0; mi < 2; ++mi) {
    #pragma unroll
    for (int i = 0; i < 4; ++i) {
      int row = gr0 + mi * 16 + kg * 4 + i;
      int bf = row / NTOK;
      float p1 = 0.f, p2 = 0.f;
      #pragma unroll
      for (int ni = 0; ni < 4; ++ni) {
        int col = w * 64 + ni * 16 + lr;
        float u = acc[mi][ni][i];
        p1 = fmaf(gelu32(u + c1[(size_t)bf * HID + col]), w2v[ni], p1);
        p2 = fmaf(gelu32(u + c2[(size_t)bf * HID + col]), w2v[ni], p2);
      }
      #pragma unroll
      for (int m = 1; m < 16; m <<= 1) { p1 += __shfl_xor(p1, m); p2 += __shfl_xor(p2, m); }
      if (lr == 0) {
        red1[mi * 16 + kg * 4 + i][w] = p1;
        red2[mi * 16 + kg * 4 + i][w] = p2;
      }
    }
  }
  __syncthreads();
  if (tid < 32) {
    float s1 = red1[tid][0] + red1[tid][1] + red1[tid][2] + red1[tid][3];
    float s2 = red2[tid][0] + red2[tid][1] + red2[tid][2] + red2[tid][3];
    scores[gr0 + tid] = tanhf(s1) + tanhf(s2);
  }
}

// ---------- K2: perturbed top-k, tail-batched RNG, early-exit search ----------
__global__ __launch_bounds__(512) void k_topk(const float* __restrict__ scores,
                                              unsigned short* __restrict__ partial) {
  const int b = blockIdx.x, chunk = blockIdx.y;
  const int tid = threadIdx.x, lane = tid & 63, wv = tid >> 6;
  __shared__ float sc_s[NTOK];
  __shared__ int cnt_s[CNTSZ];
  if (tid < NTOK) sc_s[tid] = scores[b * NTOK + tid];
  for (int i = tid; i < CNTSZ; i += 512) cnt_s[i] = 0;

  const int s_first = chunk + SPB * wv;
  const unsigned gb = (unsigned)b * NS * 196u;

  float n_tail = 0.0f;
  {
    int si = lane >> 2, t = lane & 3;
    int s = s_first + si * (SPB * 8);
    if (lane < 28 && s < NS) {
      n_tail = noise_at(gb + (unsigned)s * 196u + 192u + (unsigned)t);
    }
  }
  __syncthreads();

  int si = 0;
  for (int s = s_first; s < NS; s += SPB * 8, ++si) {
    const unsigned gbase = gb + (unsigned)s * 196u;
    unsigned key[4];
    #pragma unroll
    for (int c = 0; c < 3; ++c) {
      float n = noise_at(gbase + (unsigned)(c * 64 + lane));
      float p = fmaf(0.05f, n, sc_s[c * 64 + lane]);
      unsigned ub = __float_as_uint(p);
      key[c] = (ub & 0x80000000u) ? ~ub : (ub | 0x80000000u);
    }
    {
      float n = __shfl(n_tail, si * 4 + (lane & 3));
      float p = fmaf(0.05f, n, sc_s[192 + (lane & 3)]);
      unsigned ub = __float_as_uint(p);
      unsigned k3 = (ub & 0x80000000u) ? ~ub : (ub | 0x80000000u);
      key[3] = (lane < 4) ? k3 : 0u;
    }
    unsigned prefix = 0u;
    bool exact = false;
    for (int bit = 31; bit >= 0; --bit) {
      unsigned t = prefix | (1u << bit);
      int cn = 0;
      #pragma unroll
      for (int c = 0; c < 4; ++c) cn += __popcll(__ballot(key[c] >= t));
      if (cn >= TOPK) {
        prefix = t;
        if (cn == TOPK) { exact = true; break; }
      }
    }
    unsigned long long lt = (1ull << lane) - 1ull;
    bool sel[4];
    if (exact) {
      #pragma unroll
      for (int c = 0; c < 4; ++c) sel[c] = key[c] >= prefix;
    } else {
      unsigned long long mE[4];
      int cntG = 0;
      #pragma unroll
      for (int c = 0; c < 4; ++c) {
        cntG += __popcll(__ballot(key[c] > prefix));
        mE[c] = __ballot(key[c] == prefix);
      }
      int need = TOPK - cntG;
      #pragma unroll
      for (int c = 0; c < 4; ++c) {
        int er = 0;
        for (int cc = 0; cc < c; ++cc) er += __popcll(mE[cc]);
        er += __popcll(mE[c] & lt);
        sel[c] = (key[c] > prefix) || ((key[c] == prefix) && (er < need));
      }
    }
    unsigned long long mS[4];
    #pragma unroll
    for (int c = 0; c < 4; ++c) mS[c] = __ballot(sel[c]);
    int base = 0;
    #pragma unroll
    for (int c = 0; c < 4; ++c) {
      if (sel[c]) {
        int rank = base + __popcll(mS[c] & lt);
        int j = c * 64 + lane;
        atomicAdd(&cnt_s[rank * NTOK + j], 1);
      }
      base += __popcll(mS[c]);
    }
  }
  __syncthreads();
  unsigned short* dst = partial + ((size_t)b * SPB + chunk) * CNTSZ;
  for (int i = tid; i < CNTSZ; i += 512) dst[i] = (unsigned short)cnt_s[i];
}

// ---------- K3: out[b,k,:] = sum_l (sum_c partial)/500 * x[b,l,:] ----------
// grid transposed: bid = k*BP + b -> all 49 blocks of frame b share bid%8 (XCD L2)
__global__ __launch_bounds__(256) void k_out(const float* __restrict__ x,
                                             const unsigned short* __restrict__ partial,
                                             float* __restrict__ out) {
  int bid = blockIdx.x;
  int b = bid % BP, k = bid / BP;
  __shared__ float swv[NTOK];
  __shared__ int idxs[NTOK];
  __shared__ int wcnt[4];
  __shared__ int wbase[5];
  __shared__ float4 part2[128];
  const int tid = threadIdx.x, lane = tid & 63, wv = tid >> 6;

  int cval = 0;
  if (tid < NTOK) {
    #pragma unroll
    for (int cc = 0; cc < SPB; ++cc)
      cval += partial[((size_t)b * SPB + cc) * CNTSZ + k * NTOK + tid];
  }
  unsigned long long m = __ballot(cval != 0);
  if (lane == 0) wcnt[wv] = __popcll(m);
  __syncthreads();
  if (tid == 0) {
    int a = 0;
    #pragma unroll
    for (int i = 0; i < 4; ++i) { wbase[i] = a; a += wcnt[i]; }
    wbase[4] = a;
  }
  __syncthreads();
  if (cval != 0) {
    int pos = wbase[wv] + __popcll(m & ((1ull << lane) - 1ull));
    idxs[pos] = tid;
    swv[pos] = (float)cval * 0.002f;
  }
  __syncthreads();
  const int n = wbase[4];
  const int half = tid >> 7, d4 = tid & 127;
  const int i0 = half ? (n + 1) / 2 : 0;
  const int i1 = half ? n : (n + 1) / 2;
  float a0 = 0, a1 = 0, a2 = 0, a3 = 0;
  for (int i = i0; i < i1; ++i) {
    float w = swv[i];
    float4 xv = *(const float4*)(x + ((size_t)(b * NTOK + idxs[i])) * DIM + d4 * 4);
    a0 = fmaf(w, xv.x, a0); a1 = fmaf(w, xv.y, a1);
    a2 = fmaf(w, xv.z, a2); a3 = fmaf(w, xv.w, a3);
  }
  if (half == 1) part2[d4] = make_float4(a0, a1, a2, a3);
  __syncthreads();
  if (half == 0) {
    float4 p = part2[d4];
    float4 o = make_float4(a0 + p.x, a1 + p.y, a2 + p.z, a3 + p.w);
    *(float4*)(out + ((size_t)(b * TOPK + k)) * DIM + d4 * 4) = o;
  }
}

// ---------- launcher ----------
extern "C" void kernel_launch(void* const* d_in, const int* in_sizes, int n_in,
                              void* d_out, int out_size, void* d_ws, size_t ws_size,
                              hipStream_t stream) {
  const float* x       = (const float*)d_in[0];
  const float* gf      = (const float*)d_in[1];
  const float* gs      = (const float*)d_in[2];
  const float* ln_in_g = (const float*)d_in[3];
  const float* ln_in_b = (const float*)d_in[4];
  const float* W_in    = (const float*)d_in[5];
  const float* ln_gd_g = (const float*)d_in[6];
  const float* ln_gd_b = (const float*)d_in[7];
  const float* W_gd    = (const float*)d_in[8];
  const float* W_out1  = (const float*)d_in[9];
  const float* W_out2  = (const float*)d_in[10];
  float* out = (float*)d_out;

  // ws layout (~39.8 MB): xP (38.6 MB) is dead after k_gemm and ALIASES partial
  // (written by k_topk, strictly after k_gemm on the stream).
  char* p = (char*)d_ws;
  _Float16* xPh = (_Float16*)p;
  _Float16* xPl = xPh + (size_t)ROWS * DIM;
  unsigned short* partial = (unsigned short*)p;       // alias (18.4 MB < 38.6 MB)
  p += (size_t)ROWS * DIM * 2 * 2;                    // 38.6 MB union
  float* stats   = (float*)p;             p += (size_t)ROWS * 2 * 4;
  float* c1      = (float*)p;             p += (size_t)BP * HID * 4;
  float* c2      = (float*)p;             p += (size_t)BP * HID * 4;
  float* scores  = (float*)p;             p += (size_t)ROWS * 4;
  _Float16* Pgh  = (_Float16*)p;          p += (size_t)HID * DIM * 2;
  _Float16* Pgl  = (_Float16*)p;          p += (size_t)HID * DIM * 2;
  _Float16* P1h  = (_Float16*)p;          p += (size_t)HID * HID * 2;
  _Float16* P1l  = (_Float16*)p;          p += (size_t)HID * HID * 2;
  float* gwv     = (float*)p;             p += HID * 4;
  float* bwv     = (float*)p;             p += HID * 4;

  k_pre<<<PRE_GLOB + PRE_PREP + PRE_STATS + PRE_PACK, 256, 0, stream>>>(
      gf, gs, ln_gd_g, ln_gd_b, W_gd, W_out1, c1,
      W_in, ln_in_g, ln_in_b, Pgh, Pgl, P1h, P1l, gwv, bwv, x, stats, xPh, xPl);
  k_gemm<<<GBLK, 256, 0, stream>>>(xPh, xPl, stats, Pgh, Pgl, gwv, bwv,
                                   P1h, P1l, W_out2, c1, c2, scores);
  k_topk<<<dim3(BP, SPB), 512, 0, stream>>>(scores, partial);
  k_out<<<BP * TOPK, 256, 0, stream>>>(x, partial, out);
}